// Round 13
// baseline (47744.370 us; speedup 1.0000x reference)
//
#include <hip/hip_runtime.h>
#include <cstdint>

// ---------------- configuration ----------------
#define HDIM 250          // hidden size
#define GDIM 1000         // 4*H gate rows
#define CH   64           // chunk length (steps) for inter-WG handoff
#define PP   4            // projection WGs per layer-ring
#define HRING 2           // h ring depth (chunks)
#define XRING 2           // xw ring depth (chunks)
#define RPAD 1024         // padded gate-row dimension
#define NTH  256          // 4 waves -> allocator budget 65536/256 = 256 VGPRs

// weight quad classes per gate row (32 quads of 8 cols each):
//   k 0..9   REG   (40 quads, 160 regs)
//   k 10..18 LDS   (36 quads, 147456 B)
//   k 19..31 STREAM(52 quads, 212992 B/step from L2, prepacked)
#define NSTR 52
#define LDSW_BYTES (36 * NTH * 16)          // 147456
#define HB_BASE LDSW_BYTES                  // h dbuf: 2 x 512 B
#define RED_BASE (HB_BASE + 1024)           // 148480
#define SMEM_BYTES (RED_BASE + 1024)        // 149504 (proj needs 65792)

typedef _Float16 f16x2 __attribute__((ext_vector_type(2)));

__device__ __forceinline__ float fdot2u(uint32_t w, uint32_t h, float acc) {
#if defined(__has_builtin) && __has_builtin(__builtin_amdgcn_fdot2)
  return __builtin_amdgcn_fdot2(__builtin_bit_cast(f16x2, w),
                                __builtin_bit_cast(f16x2, h), acc, false);
#else
  f16x2 wv = __builtin_bit_cast(f16x2, w), hv = __builtin_bit_cast(f16x2, h);
  return acc + (float)wv[0] * (float)hv[0] + (float)wv[1] * (float)hv[1];
#endif
}

__device__ __forceinline__ uint32_t pkh2(float a, float b) {
  f16x2 p; p[0] = (_Float16)a; p[1] = (_Float16)b;
  return __builtin_bit_cast(uint32_t, p);
}

// pack 8 consecutive f32 weights (zero beyond HDIM / null row) into 4x fp16x2
__device__ __forceinline__ uint4 pack8q(const float* rp, int c0) {
  float c[8];
#pragma unroll
  for (int u = 0; u < 8; ++u) {
    int col = c0 + u;
    c[u] = (rp && col < HDIM) ? rp[col] : 0.f;
  }
  uint4 r;
  r.x = pkh2(c[0], c[1]); r.y = pkh2(c[2], c[3]);
  r.z = pkh2(c[4], c[5]); r.w = pkh2(c[6], c[7]);
  return r;
}

__device__ __forceinline__ float rcpf_(float x) {
#if defined(__has_builtin) && __has_builtin(__builtin_amdgcn_rcpf)
  return __builtin_amdgcn_rcpf(x);
#else
  return 1.f / x;
#endif
}
__device__ __forceinline__ float sigm(float x) {
  return rcpf_(1.f + exp2f(-1.44269504088896341f * x));
}
__device__ __forceinline__ float tanh_(float x) {
  float e = exp2f(2.88539008177792681f * x);
  return 1.f - 2.f * rcpf_(e + 1.f);
}

__device__ __forceinline__ void step_barrier() {
  asm volatile("s_waitcnt lgkmcnt(0)\n\ts_barrier" ::: "memory");
}

// ---------------- flags (ints, in d_ws, zeroed each launch) ----------------
#define F_HCNT(F, li)     (F)[(li)]
#define F_XWCON(F, li)    (F)[2 + (li)]
#define F_HDONE(F, li, p) (F)[4 + (li) * PP + (p)]
#define F_XWRDY(F, li, c) (F)[16 + (li) * 128 + (c)]

__device__ __forceinline__ int aload(int* p) {
  return __hip_atomic_load(p, __ATOMIC_RELAXED, __HIP_MEMORY_SCOPE_AGENT);
}
__device__ __forceinline__ void arel(int* p, int v) {
  __hip_atomic_store(p, v, __ATOMIC_RELEASE, __HIP_MEMORY_SCOPE_AGENT);
}
__device__ __forceinline__ void acq_fence() {
  __builtin_amdgcn_fence(__ATOMIC_ACQUIRE, "agent");
}
__device__ __forceinline__ void spin_ge(int* p, int tgt) {
  unsigned n = 0;
  while (aload(p) < tgt) {
    __builtin_amdgcn_s_sleep(1);
    if (++n > 20000000u) return;  // hang guard; result will fail visibly
  }
}

// ---------------- init: WT transpose, biases, stream-quad prepack ----------------
__global__ void lstm_init(const float* __restrict__ Wih1, const float* __restrict__ bih1,
                          const float* __restrict__ bhh1, const float* __restrict__ Wih2,
                          const float* __restrict__ bih2, const float* __restrict__ bhh2,
                          const float* __restrict__ Whh0, const float* __restrict__ Whh1,
                          const float* __restrict__ Whh2, float* __restrict__ WT,
                          float* __restrict__ BV, uint4* __restrict__ sbuf) {
  int idx = blockIdx.x * blockDim.x + threadIdx.x;
  int stride = gridDim.x * blockDim.x;
  for (int i = idx; i < 2 * HDIM * RPAD; i += stride) {
    int li = i / (HDIM * RPAD);
    int rem = i - li * HDIM * RPAD;
    int j = rem / RPAD, r = rem - j * RPAD;
    const float* W = li ? Wih2 : Wih1;
    WT[i] = (r < GDIM) ? W[r * HDIM + j] : 0.f;
  }
  for (int i = idx; i < 2 * RPAD; i += stride) {
    int li = i >> 10, r = i & 1023;
    const float* bi = li ? bih2 : bih1;
    const float* bh = li ? bhh2 : bhh1;
    BV[i] = (r < GDIM) ? bi[r] + bh[r] : 0.f;
  }
  // stream prepack: sbuf[L][q][t], q=(k-19)*4+g, coalesced lane-major
  for (int i = idx; i < 3 * NSTR * NTH; i += stride) {
    int L = i / (NSTR * NTH);
    int r2 = i - L * (NSTR * NTH);
    int q = r2 / NTH, t = r2 % NTH;
    int k = 19 + (q >> 2), g = q & 3;
    const float* W = (L == 0) ? Whh0 : (L == 1) ? Whh1 : Whh2;
    const float* rp =
        (t < HDIM) ? (W + ((size_t)(g * HDIM + t)) * HDIM) : (const float*)nullptr;
    sbuf[(size_t)L * NSTR * NTH + q * NTH + t] = pack8q(rp, k * 8);
  }
}

// ---------------- main persistent kernel ----------------
// blocks 0..2 : recurrent layer L on ONE CU, 256 threads; thread u owns all 4
//   gates of unit u (full 250-col dots -> no cross-lane reduce, no cross-CU
//   recurrence sync). Weights: 40 REG quads + 36 LDS quads + 52 streamed/step
//   from the L2-resident prepacked sbuf (coalesced, 8-quad rolling window).
// blocks 3..10: projection WGs (xw rings for layers 1,2), chunk protocol.
__global__ void __launch_bounds__(NTH) lstm_main(
    const float* __restrict__ x, const float* __restrict__ Wih0,
    const float* __restrict__ bih0, const float* __restrict__ bhh0,
    const float* __restrict__ Whh0, const float* __restrict__ Whh1,
    const float* __restrict__ Whh2, const float* __restrict__ Wl,
    const float* __restrict__ bl, int* __restrict__ F,
    const uint4* __restrict__ sbuf, const float* __restrict__ WT,
    const float* __restrict__ BV, float* __restrict__ hRing,
    float* __restrict__ xwRing, float* __restrict__ out, int T) {
  __shared__ __align__(16) char smem[SMEM_BYTES];
  const int tid = threadIdx.x;
  const int bid = blockIdx.x;
  const int NC = T / CH;

  if (bid < 3) {
    // ================= recurrent layer =================
    const int L = bid;
    const int u = tid;
    const bool uok = (u < HDIM);

    const float* Whh = (L == 0) ? Whh0 : (L == 1) ? Whh1 : Whh2;
#define RPg(g) (uok ? (Whh + ((size_t)((g) * HDIM + u)) * HDIM) : (const float*)nullptr)

    // 40 named REG weight quads: gate g, quad k=0..9
    uint4 w0_0, w0_1, w0_2, w0_3, w0_4, w0_5, w0_6, w0_7, w0_8, w0_9;
    uint4 w1_0, w1_1, w1_2, w1_3, w1_4, w1_5, w1_6, w1_7, w1_8, w1_9;
    uint4 w2_0, w2_1, w2_2, w2_3, w2_4, w2_5, w2_6, w2_7, w2_8, w2_9;
    uint4 w3_0, w3_1, w3_2, w3_3, w3_4, w3_5, w3_6, w3_7, w3_8, w3_9;
#define INITG(g)                                                      \
  w##g##_0 = pack8q(RPg(g), 0);  w##g##_1 = pack8q(RPg(g), 8);        \
  w##g##_2 = pack8q(RPg(g), 16); w##g##_3 = pack8q(RPg(g), 24);       \
  w##g##_4 = pack8q(RPg(g), 32); w##g##_5 = pack8q(RPg(g), 40);       \
  w##g##_6 = pack8q(RPg(g), 48); w##g##_7 = pack8q(RPg(g), 56);       \
  w##g##_8 = pack8q(RPg(g), 64); w##g##_9 = pack8q(RPg(g), 72);
    INITG(0) INITG(1) INITG(2) INITG(3)

    // LDS weight quads: k=10..18, addr (( (k-10)*4+g )*NTH + tid)*16
    for (int g = 0; g < 4; ++g)
      for (int k = 10; k < 19; ++k)
        *(uint4*)(smem + (size_t)((((k - 10) * 4 + g) * NTH) + tid) * 16) =
            pack8q(RPg(g), k * 8);

    // L0 input-projection scalars (4 gates)
    float w0g0 = 0.f, w0g1 = 0.f, w0g2 = 0.f, w0g3 = 0.f;
    float b0g0 = 0.f, b0g1 = 0.f, b0g2 = 0.f, b0g3 = 0.f;
    if (L == 0 && uok) {
      w0g0 = Wih0[u];           b0g0 = bih0[u] + bhh0[u];
      w0g1 = Wih0[HDIM + u];    b0g1 = bih0[HDIM + u] + bhh0[HDIM + u];
      w0g2 = Wih0[2*HDIM + u];  b0g2 = bih0[2*HDIM + u] + bhh0[2*HDIM + u];
      w0g3 = Wih0[3*HDIM + u];  b0g3 = bih0[3*HDIM + u] + bhh0[3*HDIM + u];
    }

    // zero both h parities (incl. pad 250..255)
    if (tid < 128) ((uint2*)(smem + HB_BASE))[tid] = make_uint2(0u, 0u);
    __syncthreads();

    const uint4* sp = sbuf + (size_t)L * NSTR * NTH + tid;
    const float* xwBase = xwRing + (size_t)(L > 0 ? L - 1 : 0) * XRING * CH * RPAD;
    float* hBase = hRing + (size_t)L * HRING * CH * HDIM;
    float c_st = 0.f, h_last = 0.f;

    for (int tt = 0; tt < T; ++tt) {
      const int tc = tt & (CH - 1);
      const int c = tt >> 6;
      const int p = tt & 1, ns = p ^ 1;
      if (tc == 0) {  // chunk boundary: input ready / ring backpressure
        if (tid == 0) {
          if (L > 0) spin_ge(&F_XWRDY(F, L - 1, c), 1);
          if (L < 2 && c >= HRING)
            spin_ge(&F_HDONE(F, L, (c - HRING) % PP), c - HRING + 1);
          acq_fence();
        }
        __syncthreads();
      }

      // gate inputs (VMEM issued early, consumed after the dots)
      float xw0, xw1, xw2, xw3;
      if (L == 0) {
        float xt = x[tt];
        xw0 = fmaf(xt, w0g0, b0g0); xw1 = fmaf(xt, w0g1, b0g1);
        xw2 = fmaf(xt, w0g2, b0g2); xw3 = fmaf(xt, w0g3, b0g3);
      } else {
        const float* xp = xwBase + (size_t)(c & (XRING - 1)) * CH * RPAD +
                          (size_t)tc * RPAD;
        xw0 = xp[u]; xw1 = xp[HDIM + u]; xw2 = xp[2*HDIM + u]; xw3 = xp[3*HDIM + u];
      }

      const uint4* hb = (const uint4*)(smem + HB_BASE + p * 512);
      float a0 = 0.f, a1 = 0.f, a2 = 0.f, a3 = 0.f;

#define FD4(W_, H_, A_)                \
  A_ = fdot2u((W_).x, (H_).x, A_);     \
  A_ = fdot2u((W_).y, (H_).y, A_);     \
  A_ = fdot2u((W_).z, (H_).z, A_);     \
  A_ = fdot2u((W_).w, (H_).w, A_);
#define LDR(r)                                      \
  const uint4 s##r##_0 = sp[((r) * 4 + 0) * NTH],   \
              s##r##_1 = sp[((r) * 4 + 1) * NTH],   \
              s##r##_2 = sp[((r) * 4 + 2) * NTH],   \
              s##r##_3 = sp[((r) * 4 + 3) * NTH];
#define CONS(r)                                     \
  {                                                 \
    const uint4 hq = hb[19 + (r)];                  \
    FD4(s##r##_0, hq, a0) FD4(s##r##_1, hq, a1)     \
    FD4(s##r##_2, hq, a2) FD4(s##r##_3, hq, a3)     \
  }
#define DOTREG(k)                                   \
  {                                                 \
    const uint4 hq = hb[k];                         \
    FD4(w0_##k, hq, a0) FD4(w1_##k, hq, a1)         \
    FD4(w2_##k, hq, a2) FD4(w3_##k, hq, a3)         \
  }
#define DOTLDS(k)                                                            \
  {                                                                          \
    const uint4 hq = hb[k];                                                  \
    uint4 t0 = *(const uint4*)(smem + (size_t)(((((k)-10) * 4 + 0) * NTH) + tid) * 16); \
    FD4(t0, hq, a0)                                                          \
    uint4 t1 = *(const uint4*)(smem + (size_t)(((((k)-10) * 4 + 1) * NTH) + tid) * 16); \
    FD4(t1, hq, a1)                                                          \
    uint4 t2 = *(const uint4*)(smem + (size_t)(((((k)-10) * 4 + 2) * NTH) + tid) * 16); \
    FD4(t2, hq, a2)                                                          \
    uint4 t3 = *(const uint4*)(smem + (size_t)(((((k)-10) * 4 + 3) * NTH) + tid) * 16); \
    FD4(t3, hq, a3)                                                          \
  }

      // interleaved schedule: 13 stream rounds of 4 quads, 8-quad window,
      // REG/LDS dots fill the L2-latency gaps
      LDR(0) LDR(1)
      DOTREG(0) DOTREG(1)
      LDR(2) DOTREG(2) DOTREG(3)
      CONS(0) LDR(3) DOTREG(4) DOTREG(5)
      CONS(1) LDR(4) DOTREG(6) DOTREG(7)
      CONS(2) LDR(5) DOTREG(8) DOTREG(9)
      CONS(3) LDR(6) DOTLDS(10) DOTLDS(11)
      CONS(4) LDR(7) DOTLDS(12) DOTLDS(13)
      CONS(5) LDR(8) DOTLDS(14) DOTLDS(15)
      CONS(6) LDR(9) DOTLDS(16) DOTLDS(17)
      CONS(7) LDR(10) DOTLDS(18)
      CONS(8) LDR(11)
      CONS(9) LDR(12)
      CONS(10) CONS(11) CONS(12)

      a0 += xw0; a1 += xw1; a2 += xw2; a3 += xw3;

      // LSTM update (fully thread-local)
      const float ii = sigm(a0), ff = sigm(a1), tg = tanh_(a2), oo = sigm(a3);
      c_st = ff * c_st + ii * tg;
      const float hn = oo * tanh_(c_st);
      h_last = hn;

      if (uok) {
        *(_Float16*)(smem + HB_BASE + ns * 512 + u * 2) = (_Float16)hn;
        if (L < 2)
          hBase[(size_t)(c & (HRING - 1)) * CH * HDIM + (size_t)tc * HDIM + u] = hn;
      }

      if (tc == CH - 1) {  // chunk end: drain stores, publish flags
        asm volatile("s_waitcnt vmcnt(0)" ::: "memory");
        __syncthreads();
        if (tid == 0) {
          if (L < 2) arel(&F_HCNT(F, L), c + 1);
          if (L > 0) arel(&F_XWCON(F, L - 1), c + 1);
        }
        __syncthreads();
      } else {
        step_barrier();  // lgkm-only: h parity write visible to next step
      }
    }

    if (L == 2) {  // final linear on h2[T-1]
      float* red = (float*)(smem + RED_BASE);
      if (uok) red[u] = h_last * Wl[u];
      __syncthreads();
      if (tid == 0) {
        float s = bl[0];
        for (int j = 0; j < HDIM; ++j) s += red[j];
        out[0] = s;
      }
    }
  } else {
    // ================= projection role (256 threads, 4 waves) =================
    const int li = (bid - 3) / PP;
    const int p = (bid - 3) % PP;
    float* ldsH = (float*)smem;  // [64][257] f32
    const int lane = tid & 63, wid = tid >> 6;
    const float* WTl = WT + (size_t)li * HDIM * RPAD;
    const float* BVl = BV + (size_t)li * RPAD;

    for (int c = p; c < NC; c += PP) {
      if (tid == 0) {
        spin_ge(&F_HCNT(F, li), c + 1);
        if (c >= XRING) spin_ge(&F_XWCON(F, li), c - XRING + 1);
        acq_fence();
      }
      __syncthreads();
      const float* hsrc = hRing + (size_t)li * HRING * CH * HDIM +
                          (size_t)(c & (HRING - 1)) * CH * HDIM;
      for (int t = wid; t < CH; t += 4)
        for (int j = lane; j < HDIM; j += 64)
          ldsH[t * 257 + j] = hsrc[t * HDIM + j];
      __syncthreads();
      if (tid == 0) arel(&F_HDONE(F, li, p), c + 1);

      float* xdst = xwRing + (size_t)li * XRING * CH * RPAD +
                    (size_t)(c & (XRING - 1)) * CH * RPAD;
      const int rb0 = wid * 256;  // 4 waves x 256 rows
      for (int grpq = 0; grpq < 32; ++grpq) {
        const int rb = rb0 + grpq * 8;
        float acc[8];
#pragma unroll
        for (int uq = 0; uq < 8; ++uq) acc[uq] = 0.f;
        const float* wp = WTl + rb;
        float4 wa4 = *(const float4*)(wp);
        float4 wb4 = *(const float4*)(wp + 4);
        for (int j = 0; j < HDIM; ++j) {
          int jn = (j + 1 < HDIM) ? j + 1 : HDIM - 1;
          float4 na = *(const float4*)(wp + (size_t)jn * RPAD);
          float4 nb = *(const float4*)(wp + (size_t)jn * RPAD + 4);
          float hj = ldsH[lane * 257 + j];
          acc[0] = fmaf(wa4.x, hj, acc[0]); acc[1] = fmaf(wa4.y, hj, acc[1]);
          acc[2] = fmaf(wa4.z, hj, acc[2]); acc[3] = fmaf(wa4.w, hj, acc[3]);
          acc[4] = fmaf(wb4.x, hj, acc[4]); acc[5] = fmaf(wb4.y, hj, acc[5]);
          acc[6] = fmaf(wb4.z, hj, acc[6]); acc[7] = fmaf(wb4.w, hj, acc[7]);
          wa4 = na; wb4 = nb;
        }
#pragma unroll
        for (int uq = 0; uq < 8; ++uq) {
          int r = rb + uq;
          if (r < GDIM) xdst[(size_t)lane * RPAD + r] = acc[uq] + BVl[r];
        }
      }
      __syncthreads();
      if (tid == 0) arel(&F_XWRDY(F, li, c), 1);
    }
  }
}

// ---------------- launch ----------------
extern "C" void kernel_launch(void* const* d_in, const int* in_sizes, int n_in,
                              void* d_out, int out_size, void* d_ws, size_t ws_size,
                              hipStream_t stream) {
  const float* x    = (const float*)d_in[0];
  const float* Wih0 = (const float*)d_in[1];
  const float* Whh0 = (const float*)d_in[2];
  const float* bih0 = (const float*)d_in[3];
  const float* bhh0 = (const float*)d_in[4];
  const float* Wih1 = (const float*)d_in[5];
  const float* Whh1 = (const float*)d_in[6];
  const float* bih1 = (const float*)d_in[7];
  const float* bhh1 = (const float*)d_in[8];
  const float* Wih2 = (const float*)d_in[9];
  const float* Whh2 = (const float*)d_in[10];
  const float* bih2 = (const float*)d_in[11];
  const float* bhh2 = (const float*)d_in[12];
  const float* Wl   = (const float*)d_in[13];
  const float* bl   = (const float*)d_in[14];
  const int T = in_sizes[0];

  char* ws = (char*)d_ws;
  int*   F    = (int*)ws;                         // 4,096 B flags
  float* WT   = (float*)(ws + 4096);              // 2,048,000 B
  float* BV   = (float*)(ws + 2052096);           // 8,192 B
  uint4* sbuf = (uint4*)(ws + 2060288);           // 3*52*256*16 = 638,976 B
  float* hR   = (float*)(ws + 2699264);           // 2*2*64*250*4 = 256,000 B
  float* xwR  = (float*)(ws + 2955264);           // 2*2*64*1024*4 = 1,048,576 B
                                                  // end: 4,003,840 B

  hipMemsetAsync(F, 0, 4096, stream);  // reset protocol state every replay
  lstm_init<<<256, 256, 0, stream>>>(Wih1, bih1, bhh1, Wih2, bih2, bhh2,
                                     Whh0, Whh1, Whh2, WT, BV, sbuf);
  lstm_main<<<3 + 2 * PP, NTH, 0, stream>>>(
      x, Wih0, bih0, bhh0, Whh0, Whh1, Whh2, Wl, bl, F, sbuf, WT, BV, hR, xwR,
      (float*)d_out, T);
}

// Round 14
// 43384.866 us; speedup vs baseline: 1.1005x; 1.1005x over previous
//
#include <hip/hip_runtime.h>
#include <cstdint>

// ---------------- configuration ----------------
#define HDIM 250          // hidden size
#define GDIM 1000         // 4*H gate rows
#define CH   64           // chunk length (steps) for inter-WG handoff
#define PP   4            // projection WGs per layer-ring
#define HRING 2           // h ring depth (chunks)
#define XRING 2           // xw ring depth (chunks)
#define RPAD 1024         // padded gate-row dimension
#define NTH  256          // 4 waves = 1 wave/SIMD (1 WG/CU via 146KB LDS)

// weight quad classes per gate row (32 quads of 8 cols each):
//   k 0..10  ARCH VGPR (44 quads, 176 regs)
//   k 11..22 AGPR      (48 quads, 192 acc regs via hard "a" constraints)
//   k 23..31 LDS       (36 quads, 147456 B)
#define LDSW_BYTES (36 * NTH * 16)          // 147456
#define HB_BASE LDSW_BYTES                  // h dbuf: 2 x 512 B
#define RED_BASE (HB_BASE + 1024)           // 148480
#define SMEM_BYTES (RED_BASE + 1024)        // 149504 (proj needs 65792)

typedef _Float16 f16x2 __attribute__((ext_vector_type(2)));

__device__ __forceinline__ float fdot2u(uint32_t w, uint32_t h, float acc) {
#if defined(__has_builtin) && __has_builtin(__builtin_amdgcn_fdot2)
  return __builtin_amdgcn_fdot2(__builtin_bit_cast(f16x2, w),
                                __builtin_bit_cast(f16x2, h), acc, false);
#else
  f16x2 wv = __builtin_bit_cast(f16x2, w), hv = __builtin_bit_cast(f16x2, h);
  return acc + (float)wv[0] * (float)hv[0] + (float)wv[1] * (float)hv[1];
#endif
}

__device__ __forceinline__ uint32_t pkh2(float a, float b) {
  f16x2 p; p[0] = (_Float16)a; p[1] = (_Float16)b;
  return __builtin_bit_cast(uint32_t, p);
}

// pack 8 consecutive f32 weights (zero beyond HDIM / null row) into 4x fp16x2
__device__ __forceinline__ uint4 pack8q(const float* rp, int c0) {
  float c[8];
#pragma unroll
  for (int u = 0; u < 8; ++u) {
    int col = c0 + u;
    c[u] = (rp && col < HDIM) ? rp[col] : 0.f;
  }
  uint4 r;
  r.x = pkh2(c[0], c[1]); r.y = pkh2(c[2], c[3]);
  r.z = pkh2(c[4], c[5]); r.w = pkh2(c[6], c[7]);
  return r;
}

__device__ __forceinline__ float rcpf_(float x) {
#if defined(__has_builtin) && __has_builtin(__builtin_amdgcn_rcpf)
  return __builtin_amdgcn_rcpf(x);
#else
  return 1.f / x;
#endif
}
__device__ __forceinline__ float sigm(float x) {
  return rcpf_(1.f + exp2f(-1.44269504088896341f * x));
}
__device__ __forceinline__ float tanh_(float x) {
  float e = exp2f(2.88539008177792681f * x);
  return 1.f - 2.f * rcpf_(e + 1.f);
}

__device__ __forceinline__ void step_barrier() {
  asm volatile("s_waitcnt lgkmcnt(0)\n\ts_barrier" ::: "memory");
}

// ---------------- flags (ints, in d_ws, zeroed each launch) ----------------
#define F_HCNT(F, li)     (F)[(li)]
#define F_XWCON(F, li)    (F)[2 + (li)]
#define F_HDONE(F, li, p) (F)[4 + (li) * PP + (p)]
#define F_XWRDY(F, li, c) (F)[16 + (li) * 128 + (c)]

__device__ __forceinline__ int aload(int* p) {
  return __hip_atomic_load(p, __ATOMIC_RELAXED, __HIP_MEMORY_SCOPE_AGENT);
}
__device__ __forceinline__ void arel(int* p, int v) {
  __hip_atomic_store(p, v, __ATOMIC_RELEASE, __HIP_MEMORY_SCOPE_AGENT);
}
__device__ __forceinline__ void acq_fence() {
  __builtin_amdgcn_fence(__ATOMIC_ACQUIRE, "agent");
}
__device__ __forceinline__ void spin_ge(int* p, int tgt) {
  unsigned n = 0;
  while (aload(p) < tgt) {
    __builtin_amdgcn_s_sleep(1);
    if (++n > 20000000u) return;  // hang guard; result will fail visibly
  }
}

// ---------------- init: transpose Wih1/2 -> WT[li][j][RPAD], biases ----------------
__global__ void lstm_init(const float* __restrict__ Wih1, const float* __restrict__ bih1,
                          const float* __restrict__ bhh1, const float* __restrict__ Wih2,
                          const float* __restrict__ bih2, const float* __restrict__ bhh2,
                          float* __restrict__ WT, float* __restrict__ BV) {
  int idx = blockIdx.x * blockDim.x + threadIdx.x;
  int stride = gridDim.x * blockDim.x;
  for (int i = idx; i < 2 * HDIM * RPAD; i += stride) {
    int li = i / (HDIM * RPAD);
    int rem = i - li * HDIM * RPAD;
    int j = rem / RPAD, r = rem - j * RPAD;
    const float* W = li ? Wih2 : Wih1;
    WT[i] = (r < GDIM) ? W[r * HDIM + j] : 0.f;
  }
  for (int i = idx; i < 2 * RPAD; i += stride) {
    int li = i >> 10, r = i & 1023;
    const float* bi = li ? bih2 : bih1;
    const float* bh = li ? bhh2 : bhh1;
    BV[i] = (r < GDIM) ? bi[r] + bh[r] : 0.f;
  }
}

// ---------------- main persistent kernel ----------------
// blocks 0..2 : recurrent layer L on ONE CU, 256 threads; thread u owns all 4
//   gates of unit u (full 250-col dots; no cross-lane reduce; no cross-CU
//   per-step sync). ALL Whh weights CU-resident in fp16:
//   44 quads arch VGPR + 48 quads AGPR (named, hard "a" asm constraints,
//   immune to the allocator's 2-block budget heuristic) + 36 quads LDS.
// blocks 3..10: projection WGs (xw rings for layers 1,2), chunk protocol.
__global__ void __launch_bounds__(NTH) lstm_main(
    const float* __restrict__ x, const float* __restrict__ Wih0,
    const float* __restrict__ bih0, const float* __restrict__ bhh0,
    const float* __restrict__ Whh0, const float* __restrict__ Whh1,
    const float* __restrict__ Whh2, const float* __restrict__ Wl,
    const float* __restrict__ bl, int* __restrict__ F,
    const float* __restrict__ WT, const float* __restrict__ BV,
    float* __restrict__ hRing, float* __restrict__ xwRing,
    float* __restrict__ out, int T) {
  __shared__ __align__(16) char smem[SMEM_BYTES];
  const int tid = threadIdx.x;
  const int bid = blockIdx.x;
  const int NC = T / CH;

  if (bid < 3) {
    // ================= recurrent layer =================
    const int L = bid;
    const int u = tid;
    const bool uok = (u < HDIM);

    const float* Whh = (L == 0) ? Whh0 : (L == 1) ? Whh1 : Whh2;
#define RPg(g) (uok ? (Whh + ((size_t)((g) * HDIM + u)) * HDIM) : (const float*)nullptr)

    // ---- 44 named ARCH weight quads: gate g, k = 0..10 ----
#define DECLV(g)                                                              \
  uint4 wA##g##_0, wA##g##_1, wA##g##_2, wA##g##_3, wA##g##_4, wA##g##_5,     \
      wA##g##_6, wA##g##_7, wA##g##_8, wA##g##_9, wA##g##_10;
    DECLV(0) DECLV(1) DECLV(2) DECLV(3)
#define IV(g, k) wA##g##_##k = pack8q(RPg(g), (k) * 8);
#define INITV(g)                                                        \
  IV(g, 0) IV(g, 1) IV(g, 2) IV(g, 3) IV(g, 4) IV(g, 5) IV(g, 6)        \
  IV(g, 7) IV(g, 8) IV(g, 9) IV(g, 10)
    INITV(0) INITV(1) INITV(2) INITV(3)

    // ---- 48 AGPR weight quads (192 named acc dwords): k = 11..22 ----
#define DECLA(g, k)                                                     \
  uint32_t ag##g##_##k##_0, ag##g##_##k##_1, ag##g##_##k##_2, ag##g##_##k##_3;
#define DECLAG(g)                                                       \
  DECLA(g, 11) DECLA(g, 12) DECLA(g, 13) DECLA(g, 14) DECLA(g, 15)      \
  DECLA(g, 16) DECLA(g, 17) DECLA(g, 18) DECLA(g, 19) DECLA(g, 20)      \
  DECLA(g, 21) DECLA(g, 22)
    DECLAG(0) DECLAG(1) DECLAG(2) DECLAG(3)
#define IA(g, k)                                                              \
  {                                                                           \
    uint4 q = pack8q(RPg(g), (k) * 8);                                        \
    asm volatile("v_accvgpr_write_b32 %0, %1" : "=a"(ag##g##_##k##_0) : "v"(q.x)); \
    asm volatile("v_accvgpr_write_b32 %0, %1" : "=a"(ag##g##_##k##_1) : "v"(q.y)); \
    asm volatile("v_accvgpr_write_b32 %0, %1" : "=a"(ag##g##_##k##_2) : "v"(q.z)); \
    asm volatile("v_accvgpr_write_b32 %0, %1" : "=a"(ag##g##_##k##_3) : "v"(q.w)); \
  }
#define INITA(g)                                                        \
  IA(g, 11) IA(g, 12) IA(g, 13) IA(g, 14) IA(g, 15) IA(g, 16)           \
  IA(g, 17) IA(g, 18) IA(g, 19) IA(g, 20) IA(g, 21) IA(g, 22)
    INITA(0) INITA(1) INITA(2) INITA(3)

    // ---- 36 LDS weight quads: k = 23..31, slot ((k-23)*4+g)*NTH + tid ----
    for (int g = 0; g < 4; ++g)
      for (int k = 23; k < 32; ++k)
        *(uint4*)(smem + (size_t)((((k - 23) * 4 + g) * NTH) + tid) * 16) =
            pack8q(RPg(g), k * 8);

    // L0 input-projection scalars (4 gates)
    float w0g0 = 0.f, w0g1 = 0.f, w0g2 = 0.f, w0g3 = 0.f;
    float b0g0 = 0.f, b0g1 = 0.f, b0g2 = 0.f, b0g3 = 0.f;
    if (L == 0 && uok) {
      w0g0 = Wih0[u];           b0g0 = bih0[u] + bhh0[u];
      w0g1 = Wih0[HDIM + u];    b0g1 = bih0[HDIM + u] + bhh0[HDIM + u];
      w0g2 = Wih0[2*HDIM + u];  b0g2 = bih0[2*HDIM + u] + bhh0[2*HDIM + u];
      w0g3 = Wih0[3*HDIM + u];  b0g3 = bih0[3*HDIM + u] + bhh0[3*HDIM + u];
    }

    // zero both h parities (incl. pad 250..255)
    if (tid < 128) ((uint2*)(smem + HB_BASE))[tid] = make_uint2(0u, 0u);
    __syncthreads();

    const float* xwBase = xwRing + (size_t)(L > 0 ? L - 1 : 0) * XRING * CH * RPAD;
    float* hBase = hRing + (size_t)L * HRING * CH * HDIM;
    float c_st = 0.f, h_last = 0.f;

#pragma unroll 1
    for (int tt = 0; tt < T; ++tt) {
      const int tc = tt & (CH - 1);
      const int c = tt >> 6;
      const int p = tt & 1, ns = p ^ 1;
      if (tc == 0) {  // chunk boundary: input ready / ring backpressure
        if (tid == 0) {
          if (L > 0) spin_ge(&F_XWRDY(F, L - 1, c), 1);
          if (L < 2 && c >= HRING)
            spin_ge(&F_HDONE(F, L, (c - HRING) % PP), c - HRING + 1);
          acq_fence();
        }
        __syncthreads();
      }

      // gate inputs (VMEM issued early, consumed after the dots)
      float xw0, xw1, xw2, xw3;
      if (L == 0) {
        float xt = x[tt];
        xw0 = fmaf(xt, w0g0, b0g0); xw1 = fmaf(xt, w0g1, b0g1);
        xw2 = fmaf(xt, w0g2, b0g2); xw3 = fmaf(xt, w0g3, b0g3);
      } else {
        const float* xp = xwBase + (size_t)(c & (XRING - 1)) * CH * RPAD +
                          (size_t)tc * RPAD;
        xw0 = xp[u]; xw1 = xp[HDIM + u]; xw2 = xp[2*HDIM + u]; xw3 = xp[3*HDIM + u];
      }

      const uint4* hb = (const uint4*)(smem + HB_BASE + p * 512);
      float a0 = 0.f, a1 = 0.f, a2 = 0.f, a3 = 0.f;

#define FD4(W_, H_, A_)                \
  A_ = fdot2u((W_).x, (H_).x, A_);     \
  A_ = fdot2u((W_).y, (H_).y, A_);     \
  A_ = fdot2u((W_).z, (H_).z, A_);     \
  A_ = fdot2u((W_).w, (H_).w, A_);
#define DOTV(k)                                     \
  {                                                 \
    const uint4 hq = hb[k];                         \
    FD4(wA0_##k, hq, a0) FD4(wA1_##k, hq, a1)       \
    FD4(wA2_##k, hq, a2) FD4(wA3_##k, hq, a3)       \
  }
#define AGD(g, k, A_)                                                          \
  {                                                                            \
    uint32_t r0, r1, r2, r3;                                                   \
    asm volatile("v_accvgpr_read_b32 %0, %1" : "=v"(r0) : "a"(ag##g##_##k##_0)); \
    asm volatile("v_accvgpr_read_b32 %0, %1" : "=v"(r1) : "a"(ag##g##_##k##_1)); \
    asm volatile("v_accvgpr_read_b32 %0, %1" : "=v"(r2) : "a"(ag##g##_##k##_2)); \
    asm volatile("v_accvgpr_read_b32 %0, %1" : "=v"(r3) : "a"(ag##g##_##k##_3)); \
    A_ = fdot2u(r0, hq.x, A_); A_ = fdot2u(r1, hq.y, A_);                      \
    A_ = fdot2u(r2, hq.z, A_); A_ = fdot2u(r3, hq.w, A_);                      \
  }
#define DOTA(k)                                     \
  {                                                 \
    const uint4 hq = hb[k];                         \
    AGD(0, k, a0) AGD(1, k, a1)                     \
    AGD(2, k, a2) AGD(3, k, a3)                     \
  }
#define DOTL(k)                                                               \
  {                                                                           \
    const uint4 hq = hb[k];                                                   \
    uint4 t0 = *(const uint4*)(smem + (size_t)(((((k)-23) * 4 + 0) * NTH) + tid) * 16); \
    FD4(t0, hq, a0)                                                           \
    uint4 t1 = *(const uint4*)(smem + (size_t)(((((k)-23) * 4 + 1) * NTH) + tid) * 16); \
    FD4(t1, hq, a1)                                                           \
    uint4 t2 = *(const uint4*)(smem + (size_t)(((((k)-23) * 4 + 2) * NTH) + tid) * 16); \
    FD4(t2, hq, a2)                                                           \
    uint4 t3 = *(const uint4*)(smem + (size_t)(((((k)-23) * 4 + 3) * NTH) + tid) * 16); \
    FD4(t3, hq, a3)                                                           \
  }

      DOTV(0) DOTV(1) DOTV(2) DOTV(3) DOTV(4) DOTV(5)
      DOTV(6) DOTV(7) DOTV(8) DOTV(9) DOTV(10)
      DOTA(11) DOTA(12) DOTA(13) DOTA(14) DOTA(15) DOTA(16)
      DOTA(17) DOTA(18) DOTA(19) DOTA(20) DOTA(21) DOTA(22)
      DOTL(23) DOTL(24) DOTL(25) DOTL(26) DOTL(27)
      DOTL(28) DOTL(29) DOTL(30) DOTL(31)

      a0 += xw0; a1 += xw1; a2 += xw2; a3 += xw3;

      // LSTM update (fully thread-local)
      const float ii = sigm(a0), ff = sigm(a1), tg = tanh_(a2), oo = sigm(a3);
      c_st = ff * c_st + ii * tg;
      const float hn = oo * tanh_(c_st);
      h_last = hn;

      if (uok) {
        *(_Float16*)(smem + HB_BASE + ns * 512 + u * 2) = (_Float16)hn;
        if (L < 2)
          hBase[(size_t)(c & (HRING - 1)) * CH * HDIM + (size_t)tc * HDIM + u] = hn;
      }

      if (tc == CH - 1) {  // chunk end: drain stores, publish flags
        asm volatile("s_waitcnt vmcnt(0)" ::: "memory");
        __syncthreads();
        if (tid == 0) {
          if (L < 2) arel(&F_HCNT(F, L), c + 1);
          if (L > 0) arel(&F_XWCON(F, L - 1), c + 1);
        }
        __syncthreads();
      } else {
        step_barrier();  // lgkm-only: h parity write visible to next step
      }
    }

    if (L == 2) {  // final linear on h2[T-1]
      float* red = (float*)(smem + RED_BASE);
      if (uok) red[u] = h_last * Wl[u];
      __syncthreads();
      if (tid == 0) {
        float s = bl[0];
        for (int j = 0; j < HDIM; ++j) s += red[j];
        out[0] = s;
      }
    }
  } else {
    // ================= projection role (256 threads, 4 waves) =================
    const int li = (bid - 3) / PP;
    const int p = (bid - 3) % PP;
    float* ldsH = (float*)smem;  // [64][257] f32
    const int lane = tid & 63, wid = tid >> 6;
    const float* WTl = WT + (size_t)li * HDIM * RPAD;
    const float* BVl = BV + (size_t)li * RPAD;

    for (int c = p; c < NC; c += PP) {
      if (tid == 0) {
        spin_ge(&F_HCNT(F, li), c + 1);
        if (c >= XRING) spin_ge(&F_XWCON(F, li), c - XRING + 1);
        acq_fence();
      }
      __syncthreads();
      const float* hsrc = hRing + (size_t)li * HRING * CH * HDIM +
                          (size_t)(c & (HRING - 1)) * CH * HDIM;
      for (int t = wid; t < CH; t += 4)
        for (int j = lane; j < HDIM; j += 64)
          ldsH[t * 257 + j] = hsrc[t * HDIM + j];
      __syncthreads();
      if (tid == 0) arel(&F_HDONE(F, li, p), c + 1);

      float* xdst = xwRing + (size_t)li * XRING * CH * RPAD +
                    (size_t)(c & (XRING - 1)) * CH * RPAD;
      const int rb0 = wid * 256;  // 4 waves x 256 rows
      for (int grpq = 0; grpq < 32; ++grpq) {
        const int rb = rb0 + grpq * 8;
        float acc[8];
#pragma unroll
        for (int uq = 0; uq < 8; ++uq) acc[uq] = 0.f;
        const float* wp = WTl + rb;
        float4 wa4 = *(const float4*)(wp);
        float4 wb4 = *(const float4*)(wp + 4);
        for (int j = 0; j < HDIM; ++j) {
          int jn = (j + 1 < HDIM) ? j + 1 : HDIM - 1;
          float4 na = *(const float4*)(wp + (size_t)jn * RPAD);
          float4 nb = *(const float4*)(wp + (size_t)jn * RPAD + 4);
          float hj = ldsH[lane * 257 + j];
          acc[0] = fmaf(wa4.x, hj, acc[0]); acc[1] = fmaf(wa4.y, hj, acc[1]);
          acc[2] = fmaf(wa4.z, hj, acc[2]); acc[3] = fmaf(wa4.w, hj, acc[3]);
          acc[4] = fmaf(wb4.x, hj, acc[4]); acc[5] = fmaf(wb4.y, hj, acc[5]);
          acc[6] = fmaf(wb4.z, hj, acc[6]); acc[7] = fmaf(wb4.w, hj, acc[7]);
          wa4 = na; wb4 = nb;
        }
#pragma unroll
        for (int uq = 0; uq < 8; ++uq) {
          int r = rb + uq;
          if (r < GDIM) xdst[(size_t)lane * RPAD + r] = acc[uq] + BVl[r];
        }
      }
      __syncthreads();
      if (tid == 0) arel(&F_XWRDY(F, li, c), 1);
    }
  }
}

// ---------------- launch ----------------
extern "C" void kernel_launch(void* const* d_in, const int* in_sizes, int n_in,
                              void* d_out, int out_size, void* d_ws, size_t ws_size,
                              hipStream_t stream) {
  const float* x    = (const float*)d_in[0];
  const float* Wih0 = (const float*)d_in[1];
  const float* Whh0 = (const float*)d_in[2];
  const float* bih0 = (const float*)d_in[3];
  const float* bhh0 = (const float*)d_in[4];
  const float* Wih1 = (const float*)d_in[5];
  const float* Whh1 = (const float*)d_in[6];
  const float* bih1 = (const float*)d_in[7];
  const float* bhh1 = (const float*)d_in[8];
  const float* Wih2 = (const float*)d_in[9];
  const float* Whh2 = (const float*)d_in[10];
  const float* bih2 = (const float*)d_in[11];
  const float* bhh2 = (const float*)d_in[12];
  const float* Wl   = (const float*)d_in[13];
  const float* bl   = (const float*)d_in[14];
  const int T = in_sizes[0];

  char* ws = (char*)d_ws;
  int*   F   = (int*)ws;                          // 4,096 B flags
  float* WT  = (float*)(ws + 4096);               // 2,048,000 B
  float* BV  = (float*)(ws + 2052096);            // 8,192 B
  float* hR  = (float*)(ws + 2060288);            // 2*2*64*250*4 = 256,000 B
  float* xwR = (float*)(ws + 2316288);            // 2*2*64*1024*4 = 1,048,576 B
                                                  // end: 3,364,864 B

  hipMemsetAsync(F, 0, 4096, stream);  // reset protocol state every replay
  lstm_init<<<256, 256, 0, stream>>>(Wih1, bih1, bhh1, Wih2, bih2, bhh2, WT, BV);
  lstm_main<<<3 + 2 * PP, NTH, 0, stream>>>(
      x, Wih0, bih0, bhh0, Whh0, Whh1, Whh2, Wl, bl, F, WT, BV, hR, xwR,
      (float*)d_out, T);
}

// Round 15
// 40769.238 us; speedup vs baseline: 1.1711x; 1.0642x over previous
//
#include <hip/hip_runtime.h>
#include <cstdint>

// ---------------- configuration ----------------
#define HDIM 250          // hidden size
#define GDIM 1000         // 4*H gate rows
#define CH   64           // chunk length (steps) for inter-WG handoff
#define PP   4            // projection WGs per layer-ring
#define HRING 2           // h ring depth (chunks)
#define XRING 2           // xw ring depth (chunks)
#define RPAD 1024         // padded gate-row dimension (UNIT-major: r = 4u+g)
#define NTH  512          // 8 waves = 2 waves/SIMD (TLP) ; arch budget 128

// rec-role weight tiers per thread (2 rows x 32 quads = 64 quads):
//   k 0..9   VGPR (2x10 quads, 80 regs)
//   k 10..25 AGPR (2x16 quads, 128 acc regs, hard "a" constraints)
//   k 26..31 LDS  (2x6  quads, 98304 B)
#define LDSW_BYTES (12 * NTH * 16)          // 98304
#define HB_BASE LDSW_BYTES                  // h dbuf: 2 x 512 B
#define RED_BASE (HB_BASE + 1024)           // 99328
#define SMEM_BYTES (RED_BASE + 1024)        // 100352 -> 1 WG/CU (proj needs 65792)

typedef _Float16 f16x2 __attribute__((ext_vector_type(2)));

__device__ __forceinline__ float fdot2u(uint32_t w, uint32_t h, float acc) {
#if defined(__has_builtin) && __has_builtin(__builtin_amdgcn_fdot2)
  return __builtin_amdgcn_fdot2(__builtin_bit_cast(f16x2, w),
                                __builtin_bit_cast(f16x2, h), acc, false);
#else
  f16x2 wv = __builtin_bit_cast(f16x2, w), hv = __builtin_bit_cast(f16x2, h);
  return acc + (float)wv[0] * (float)hv[0] + (float)wv[1] * (float)hv[1];
#endif
}

__device__ __forceinline__ uint32_t pkh2(float a, float b) {
  f16x2 p; p[0] = (_Float16)a; p[1] = (_Float16)b;
  return __builtin_bit_cast(uint32_t, p);
}

// pack 8 consecutive f32 weights (zero beyond HDIM / null row) into 4x fp16x2
__device__ __forceinline__ uint4 pack8q(const float* rp, int c0) {
  float c[8];
#pragma unroll
  for (int u = 0; u < 8; ++u) {
    int col = c0 + u;
    c[u] = (rp && col < HDIM) ? rp[col] : 0.f;
  }
  uint4 r;
  r.x = pkh2(c[0], c[1]); r.y = pkh2(c[2], c[3]);
  r.z = pkh2(c[4], c[5]); r.w = pkh2(c[6], c[7]);
  return r;
}

__device__ __forceinline__ float rcpf_(float x) {
#if defined(__has_builtin) && __has_builtin(__builtin_amdgcn_rcpf)
  return __builtin_amdgcn_rcpf(x);
#else
  return 1.f / x;
#endif
}
__device__ __forceinline__ float sigm(float x) {
  return rcpf_(1.f + exp2f(-1.44269504088896341f * x));
}
__device__ __forceinline__ float tanh_(float x) {
  float e = exp2f(2.88539008177792681f * x);
  return 1.f - 2.f * rcpf_(e + 1.f);
}

// ds_swizzle xor-lane within 32-lane group (BitMode offset)
template <int IMM>
__device__ __forceinline__ float swz(float v) {
  return __builtin_bit_cast(
      float, __builtin_amdgcn_ds_swizzle(__builtin_bit_cast(int, v), IMM));
}

__device__ __forceinline__ void step_barrier() {
  asm volatile("s_waitcnt lgkmcnt(0)\n\ts_barrier" ::: "memory");
}

#define AWR(dst, src) \
  asm volatile("v_accvgpr_write_b32 %0, %1" : "=a"(dst) : "v"(src))
#define ARD(dst, src) \
  asm volatile("v_accvgpr_read_b32 %0, %1" : "=v"(dst) : "a"(src))

// ---------------- flags (ints, in d_ws, zeroed each launch) ----------------
#define F_HCNT(F, li)     (F)[(li)]
#define F_XWCON(F, li)    (F)[2 + (li)]
#define F_HDONE(F, li, p) (F)[4 + (li) * PP + (p)]
#define F_XWRDY(F, li, c) (F)[16 + (li) * 128 + (c)]

__device__ __forceinline__ int aload(int* p) {
  return __hip_atomic_load(p, __ATOMIC_RELAXED, __HIP_MEMORY_SCOPE_AGENT);
}
__device__ __forceinline__ void arel(int* p, int v) {
  __hip_atomic_store(p, v, __ATOMIC_RELEASE, __HIP_MEMORY_SCOPE_AGENT);
}
__device__ __forceinline__ void acq_fence() {
  __builtin_amdgcn_fence(__ATOMIC_ACQUIRE, "agent");
}
__device__ __forceinline__ void spin_ge(int* p, int tgt) {
  unsigned n = 0;
  while (aload(p) < tgt) {
    __builtin_amdgcn_s_sleep(1);
    if (++n > 20000000u) return;  // hang guard; result will fail visibly
  }
}

// ---------------- init: WT/BV in UNIT-major row order (r = 4u+g) ----------------
__global__ void lstm_init(const float* __restrict__ Wih1, const float* __restrict__ bih1,
                          const float* __restrict__ bhh1, const float* __restrict__ Wih2,
                          const float* __restrict__ bih2, const float* __restrict__ bhh2,
                          float* __restrict__ WT, float* __restrict__ BV) {
  int idx = blockIdx.x * blockDim.x + threadIdx.x;
  int stride = gridDim.x * blockDim.x;
  for (int i = idx; i < 2 * HDIM * RPAD; i += stride) {
    int li = i / (HDIM * RPAD);
    int rem = i - li * HDIM * RPAD;
    int j = rem / RPAD, r = rem - j * RPAD;
    const float* W = li ? Wih2 : Wih1;
    if (r < GDIM) {
      int u = r >> 2, g = r & 3;
      WT[i] = W[(size_t)(g * HDIM + u) * HDIM + j];
    } else {
      WT[i] = 0.f;
    }
  }
  for (int i = idx; i < 2 * RPAD; i += stride) {
    int li = i >> 10, r = i & 1023;
    const float* bi = li ? bih2 : bih1;
    const float* bh = li ? bhh2 : bhh1;
    if (r < GDIM) {
      int u = r >> 2, g = r & 3;
      BV[i] = bi[g * HDIM + u] + bh[g * HDIM + u];
    } else {
      BV[i] = 0.f;
    }
  }
}

// ---------------- main persistent kernel ----------------
// blocks 0..2 : recurrent layer L on ONE CU, 512 threads (2 waves/SIMD for
//   latency hiding). Thread t owns unit-major rows 2t, 2t+1; unit u's 4 gates
//   live on adjacent lanes 2u/2u+1 -> gate exchange = 1 ds_swizzle lane^1.
//   Weights fully CU-resident fp16: 20 VGPR + 32 AGPR + 12 LDS quads/thread.
// blocks 3..10: projection WGs (xw rings for layers 1,2), chunk protocol.
__global__ void __launch_bounds__(NTH) lstm_main(
    const float* __restrict__ x, const float* __restrict__ Wih0,
    const float* __restrict__ bih0, const float* __restrict__ bhh0,
    const float* __restrict__ Whh0, const float* __restrict__ Whh1,
    const float* __restrict__ Whh2, const float* __restrict__ Wl,
    const float* __restrict__ bl, int* __restrict__ F,
    const float* __restrict__ WT, const float* __restrict__ BV,
    float* __restrict__ hRing, float* __restrict__ xwRing,
    float* __restrict__ out, int T) {
  __shared__ __align__(16) char smem[SMEM_BYTES];
  const int tid = threadIdx.x;
  const int bid = blockIdx.x;
  const int NC = T / CH;

  if (bid < 3) {
    // ================= recurrent layer =================
    const int L = bid;
    const int t = tid;
    const bool tok = (t < 500);
    const int u = t >> 1;
    const int rlo = 2 * t, rhi = 2 * t + 1;  // unit-major rows

    const float* Whh = (L == 0) ? Whh0 : (L == 1) ? Whh1 : Whh2;
    const float* rpL =
        tok ? (Whh + (size_t)((rlo & 3) * HDIM + (rlo >> 2)) * HDIM) : (const float*)nullptr;
    const float* rpH =
        tok ? (Whh + (size_t)((rhi & 3) * HDIM + (rhi >> 2)) * HDIM) : (const float*)nullptr;

    // ---- VGPR tier: k = 0..9 (named) ----
    uint4 wL0, wL1, wL2, wL3, wL4, wL5, wL6, wL7, wL8, wL9;
    uint4 wH0, wH1, wH2, wH3, wH4, wH5, wH6, wH7, wH8, wH9;
#define IVK(k) wL##k = pack8q(rpL, (k) * 8); wH##k = pack8q(rpH, (k) * 8);
    IVK(0) IVK(1) IVK(2) IVK(3) IVK(4) IVK(5) IVK(6) IVK(7) IVK(8) IVK(9)

    // ---- AGPR tier: k = 10..25 (128 named acc dwords, hard "a") ----
#define DECLA(k)                                                       \
  uint32_t aL##k##_0, aL##k##_1, aL##k##_2, aL##k##_3, aH##k##_0,      \
      aH##k##_1, aH##k##_2, aH##k##_3;
    DECLA(10) DECLA(11) DECLA(12) DECLA(13) DECLA(14) DECLA(15) DECLA(16)
    DECLA(17) DECLA(18) DECLA(19) DECLA(20) DECLA(21) DECLA(22) DECLA(23)
    DECLA(24) DECLA(25)
#define IAK(k)                                                          \
  {                                                                     \
    uint4 q = pack8q(rpL, (k) * 8);                                     \
    AWR(aL##k##_0, q.x); AWR(aL##k##_1, q.y);                           \
    AWR(aL##k##_2, q.z); AWR(aL##k##_3, q.w);                           \
    q = pack8q(rpH, (k) * 8);                                           \
    AWR(aH##k##_0, q.x); AWR(aH##k##_1, q.y);                           \
    AWR(aH##k##_2, q.z); AWR(aH##k##_3, q.w);                           \
  }
    IAK(10) IAK(11) IAK(12) IAK(13) IAK(14) IAK(15) IAK(16) IAK(17)
    IAK(18) IAK(19) IAK(20) IAK(21) IAK(22) IAK(23) IAK(24) IAK(25)

    // ---- LDS tier: k = 26..31, slot ((k-26)*2+row)*NTH + tid ----
    for (int k = 26; k < 32; ++k) {
      *(uint4*)(smem + (size_t)(((k - 26) * 2 + 0) * NTH + tid) * 16) =
          pack8q(rpL, k * 8);
      *(uint4*)(smem + (size_t)(((k - 26) * 2 + 1) * NTH + tid) * 16) =
          pack8q(rpH, k * 8);
    }

    // L0 input-projection scalars (2 rows)
    float w0lo = 0.f, b0lo = 0.f, w0hi = 0.f, b0hi = 0.f;
    if (L == 0 && tok) {
      int ilo = (rlo & 3) * HDIM + (rlo >> 2);
      int ihi = (rhi & 3) * HDIM + (rhi >> 2);
      w0lo = Wih0[ilo]; b0lo = bih0[ilo] + bhh0[ilo];
      w0hi = Wih0[ihi]; b0hi = bih0[ihi] + bhh0[ihi];
    }

    // zero both h parities (incl. pad 250..255)
    if (tid < 128) ((uint2*)(smem + HB_BASE))[tid] = make_uint2(0u, 0u);
    __syncthreads();

    const float* xwBase = xwRing + (size_t)(L > 0 ? L - 1 : 0) * XRING * CH * RPAD;
    float* hBase = hRing + (size_t)L * HRING * CH * HDIM;
    float c_st = 0.f, h_last = 0.f;

#pragma unroll 1
    for (int tt = 0; tt < T; ++tt) {
      const int tc = tt & (CH - 1);
      const int c = tt >> 6;
      const int p = tt & 1, ns = p ^ 1;
      if (tc == 0) {  // chunk boundary: input ready / ring backpressure
        if (tid == 0) {
          if (L > 0) spin_ge(&F_XWRDY(F, L - 1, c), 1);
          if (L < 2 && c >= HRING)
            spin_ge(&F_HDONE(F, L, (c - HRING) % PP), c - HRING + 1);
          acq_fence();
        }
        __syncthreads();
      }

      // gate inputs (coalesced float2 in unit-major order)
      float xwlo, xwhi;
      if (L == 0) {
        float xt = x[tt];
        xwlo = fmaf(xt, w0lo, b0lo);
        xwhi = fmaf(xt, w0hi, b0hi);
      } else {
        const float* xp = xwBase + (size_t)(c & (XRING - 1)) * CH * RPAD +
                          (size_t)tc * RPAD;
        const float2 xv = *(const float2*)(xp + 2 * t);
        xwlo = xv.x; xwhi = xv.y;
      }

      const uint4* hb = (const uint4*)(smem + HB_BASE + p * 512);
      float alo = 0.f, ahi = 0.f;

#define FD4(W_, H_, A_)                \
  A_ = fdot2u((W_).x, (H_).x, A_);     \
  A_ = fdot2u((W_).y, (H_).y, A_);     \
  A_ = fdot2u((W_).z, (H_).z, A_);     \
  A_ = fdot2u((W_).w, (H_).w, A_);
#define DV(k)                           \
  {                                     \
    const uint4 hq = hb[k];             \
    FD4(wL##k, hq, alo)                 \
    FD4(wH##k, hq, ahi)                 \
  }
#define DA(k)                                                        \
  {                                                                  \
    const uint4 hq = hb[k];                                          \
    uint32_t r0, r1, r2, r3;                                         \
    ARD(r0, aL##k##_0); ARD(r1, aL##k##_1);                          \
    ARD(r2, aL##k##_2); ARD(r3, aL##k##_3);                          \
    alo = fdot2u(r0, hq.x, alo); alo = fdot2u(r1, hq.y, alo);        \
    alo = fdot2u(r2, hq.z, alo); alo = fdot2u(r3, hq.w, alo);        \
    ARD(r0, aH##k##_0); ARD(r1, aH##k##_1);                          \
    ARD(r2, aH##k##_2); ARD(r3, aH##k##_3);                          \
    ahi = fdot2u(r0, hq.x, ahi); ahi = fdot2u(r1, hq.y, ahi);        \
    ahi = fdot2u(r2, hq.z, ahi); ahi = fdot2u(r3, hq.w, ahi);        \
  }
#define DLK(k)                                                                 \
  {                                                                            \
    const uint4 hq = hb[k];                                                    \
    uint4 q0 = *(const uint4*)(smem +                                          \
        (size_t)((((k) - 26) * 2 + 0) * NTH + tid) * 16);                      \
    FD4(q0, hq, alo)                                                           \
    uint4 q1 = *(const uint4*)(smem +                                          \
        (size_t)((((k) - 26) * 2 + 1) * NTH + tid) * 16);                      \
    FD4(q1, hq, ahi)                                                           \
  }

      DV(0) DV(1) DV(2) DV(3) DV(4) DV(5) DV(6) DV(7) DV(8) DV(9)
      DA(10) DA(11) DA(12) DA(13) DA(14) DA(15) DA(16) DA(17)
      DA(18) DA(19) DA(20) DA(21) DA(22) DA(23) DA(24) DA(25)
      DLK(26) DLK(27) DLK(28) DLK(29) DLK(30) DLK(31)

      alo += xwlo; ahi += xwhi;

      // gate exchange between the unit's two adjacent lanes (xor 1)
      const float slo = swz<0x041F>(alo);
      const float shi = swz<0x041F>(ahi);
      const bool even = !(t & 1);
      const float gi = even ? alo : slo;
      const float gf = even ? ahi : shi;
      const float gg = even ? slo : alo;
      const float go = even ? shi : ahi;

      const float ii = sigm(gi), ff = sigm(gf), tg = tanh_(gg), oo = sigm(go);
      c_st = ff * c_st + ii * tg;
      const float hn = oo * tanh_(c_st);
      h_last = hn;

      if (tok && even) {
        *(_Float16*)(smem + HB_BASE + ns * 512 + u * 2) = (_Float16)hn;
        if (L < 2)
          hBase[(size_t)(c & (HRING - 1)) * CH * HDIM + (size_t)tc * HDIM + u] = hn;
      }

      if (tc == CH - 1) {  // chunk end: drain stores, publish flags
        asm volatile("s_waitcnt vmcnt(0)" ::: "memory");
        __syncthreads();
        if (tid == 0) {
          if (L < 2) arel(&F_HCNT(F, L), c + 1);
          if (L > 0) arel(&F_XWCON(F, L - 1), c + 1);
        }
        __syncthreads();
      } else {
        step_barrier();  // lgkm-only: h parity write visible to next step
      }
    }

    if (L == 2) {  // final linear on h2[T-1]
      float* red = (float*)(smem + RED_BASE);
      if (tok && !(t & 1)) red[u] = h_last * Wl[u];
      __syncthreads();
      if (tid == 0) {
        float s = bl[0];
        for (int j = 0; j < HDIM; ++j) s += red[j];
        out[0] = s;
      }
    }
  } else {
    // ================= projection role (512 threads, 8 waves) =================
    const int li = (bid - 3) / PP;
    const int p = (bid - 3) % PP;
    float* ldsH = (float*)smem;  // [64][257] f32
    const int lane = tid & 63, wid = tid >> 6;
    const float* WTl = WT + (size_t)li * HDIM * RPAD;
    const float* BVl = BV + (size_t)li * RPAD;

    for (int c = p; c < NC; c += PP) {
      if (tid == 0) {
        spin_ge(&F_HCNT(F, li), c + 1);
        if (c >= XRING) spin_ge(&F_XWCON(F, li), c - XRING + 1);
        acq_fence();
      }
      __syncthreads();
      const float* hsrc = hRing + (size_t)li * HRING * CH * HDIM +
                          (size_t)(c & (HRING - 1)) * CH * HDIM;
      for (int t2 = wid; t2 < CH; t2 += 8)
        for (int j = lane; j < HDIM; j += 64)
          ldsH[t2 * 257 + j] = hsrc[t2 * HDIM + j];
      __syncthreads();
      if (tid == 0) arel(&F_HDONE(F, li, p), c + 1);

      float* xdst = xwRing + (size_t)li * XRING * CH * RPAD +
                    (size_t)(c & (XRING - 1)) * CH * RPAD;
      const int rb0 = wid * 128;  // 8 waves x 128 rows
      for (int grpq = 0; grpq < 16; ++grpq) {
        const int rb = rb0 + grpq * 8;
        float acc[8];
#pragma unroll
        for (int uq = 0; uq < 8; ++uq) acc[uq] = 0.f;
        const float* wp = WTl + rb;
        float4 wa4 = *(const float4*)(wp);
        float4 wb4 = *(const float4*)(wp + 4);
        for (int j = 0; j < HDIM; ++j) {
          int jn = (j + 1 < HDIM) ? j + 1 : HDIM - 1;
          float4 na = *(const float4*)(wp + (size_t)jn * RPAD);
          float4 nb = *(const float4*)(wp + (size_t)jn * RPAD + 4);
          float hj = ldsH[lane * 257 + j];
          acc[0] = fmaf(wa4.x, hj, acc[0]); acc[1] = fmaf(wa4.y, hj, acc[1]);
          acc[2] = fmaf(wa4.z, hj, acc[2]); acc[3] = fmaf(wa4.w, hj, acc[3]);
          acc[4] = fmaf(wb4.x, hj, acc[4]); acc[5] = fmaf(wb4.y, hj, acc[5]);
          acc[6] = fmaf(wb4.z, hj, acc[6]); acc[7] = fmaf(wb4.w, hj, acc[7]);
          wa4 = na; wb4 = nb;
        }
#pragma unroll
        for (int uq = 0; uq < 8; ++uq) {
          int r = rb + uq;
          if (r < GDIM) xdst[(size_t)lane * RPAD + r] = acc[uq] + BVl[r];
        }
      }
      __syncthreads();
      if (tid == 0) arel(&F_XWRDY(F, li, c), 1);
    }
  }
}

// ---------------- launch ----------------
extern "C" void kernel_launch(void* const* d_in, const int* in_sizes, int n_in,
                              void* d_out, int out_size, void* d_ws, size_t ws_size,
                              hipStream_t stream) {
  const float* x    = (const float*)d_in[0];
  const float* Wih0 = (const float*)d_in[1];
  const float* Whh0 = (const float*)d_in[2];
  const float* bih0 = (const float*)d_in[3];
  const float* bhh0 = (const float*)d_in[4];
  const float* Wih1 = (const float*)d_in[5];
  const float* Whh1 = (const float*)d_in[6];
  const float* bih1 = (const float*)d_in[7];
  const float* bhh1 = (const float*)d_in[8];
  const float* Wih2 = (const float*)d_in[9];
  const float* Whh2 = (const float*)d_in[10];
  const float* bih2 = (const float*)d_in[11];
  const float* bhh2 = (const float*)d_in[12];
  const float* Wl   = (const float*)d_in[13];
  const float* bl   = (const float*)d_in[14];
  const int T = in_sizes[0];

  char* ws = (char*)d_ws;
  int*   F   = (int*)ws;                          // 4,096 B flags
  float* WT  = (float*)(ws + 4096);               // 2,048,000 B
  float* BV  = (float*)(ws + 2052096);            // 8,192 B
  float* hR  = (float*)(ws + 2060288);            // 2*2*64*250*4 = 256,000 B
  float* xwR = (float*)(ws + 2316288);            // 2*2*64*1024*4 = 1,048,576 B
                                                  // end: 3,364,864 B

  hipMemsetAsync(F, 0, 4096, stream);  // reset protocol state every replay
  lstm_init<<<256, 256, 0, stream>>>(Wih1, bih1, bhh1, Wih2, bih2, bhh2, WT, BV);
  lstm_main<<<3 + 2 * PP, NTH, 0, stream>>>(
      x, Wih0, bih0, bhh0, Whh0, Whh1, Whh2, Wl, bl, F, WT, BV, hR, xwR,
      (float*)d_out, T);
}

// Round 16
// 40468.732 us; speedup vs baseline: 1.1798x; 1.0074x over previous
//
#include <hip/hip_runtime.h>
#include <cstdint>

// ---------------- configuration ----------------
#define HDIM 250          // hidden size
#define GDIM 1000         // 4*H gate rows
#define CH   64           // chunk length (steps) for inter-WG handoff
#define PP   4            // projection WGs per layer-ring
#define HRING 2           // h ring depth (chunks)
#define XRING 2           // xw ring depth (chunks)
#define RPAD 1024         // padded gate-row dimension (UNIT-major: r = 4u+g)
#define NTH  512          // 8 waves = 2 waves/SIMD ; arch budget 128

// rec-role weight tiers per thread (2 rows x 32 quads = 64 quads):
//   k 0..9   VGPR (2x10 quads, 80 regs)
//   k 10..25 AGPR (2x16 quads, 128 acc regs, hard "a" constraints)
//   k 26..31 LDS  (2x6  quads, 98304 B)
#define LDSW_BYTES (12 * NTH * 16)          // 98304
#define HB_BASE LDSW_BYTES                  // h dbuf: 2 x 512 B
#define RED_BASE (HB_BASE + 1024)           // 99328
#define SMEM_BYTES (RED_BASE + 1024)        // 100352 -> 1 WG/CU (proj needs 65792)

typedef _Float16 f16x2 __attribute__((ext_vector_type(2)));

__device__ __forceinline__ float fdot2u(uint32_t w, uint32_t h, float acc) {
#if defined(__has_builtin) && __has_builtin(__builtin_amdgcn_fdot2)
  return __builtin_amdgcn_fdot2(__builtin_bit_cast(f16x2, w),
                                __builtin_bit_cast(f16x2, h), acc, false);
#else
  f16x2 wv = __builtin_bit_cast(f16x2, w), hv = __builtin_bit_cast(f16x2, h);
  return acc + (float)wv[0] * (float)hv[0] + (float)wv[1] * (float)hv[1];
#endif
}

__device__ __forceinline__ uint32_t pkh2(float a, float b) {
  f16x2 p; p[0] = (_Float16)a; p[1] = (_Float16)b;
  return __builtin_bit_cast(uint32_t, p);
}

// pack 8 consecutive f32 weights (zero beyond HDIM / null row) into 4x fp16x2
__device__ __forceinline__ uint4 pack8q(const float* rp, int c0) {
  float c[8];
#pragma unroll
  for (int u = 0; u < 8; ++u) {
    int col = c0 + u;
    c[u] = (rp && col < HDIM) ? rp[col] : 0.f;
  }
  uint4 r;
  r.x = pkh2(c[0], c[1]); r.y = pkh2(c[2], c[3]);
  r.z = pkh2(c[4], c[5]); r.w = pkh2(c[6], c[7]);
  return r;
}

__device__ __forceinline__ float rcpf_(float x) {
#if defined(__has_builtin) && __has_builtin(__builtin_amdgcn_rcpf)
  return __builtin_amdgcn_rcpf(x);
#else
  return 1.f / x;
#endif
}
__device__ __forceinline__ float sigm(float x) {
  return rcpf_(1.f + exp2f(-1.44269504088896341f * x));
}
__device__ __forceinline__ float tanh_(float x) {
  float e = exp2f(2.88539008177792681f * x);
  return 1.f - 2.f * rcpf_(e + 1.f);
}

// ds_swizzle xor-lane within 32-lane group (BitMode offset)
template <int IMM>
__device__ __forceinline__ float swz(float v) {
  return __builtin_bit_cast(
      float, __builtin_amdgcn_ds_swizzle(__builtin_bit_cast(int, v), IMM));
}

__device__ __forceinline__ void step_barrier() {
  asm volatile("s_waitcnt lgkmcnt(0)\n\ts_barrier" ::: "memory");
}

#define AWR(dst, src) \
  asm volatile("v_accvgpr_write_b32 %0, %1" : "=a"(dst) : "v"(src))

// ---------------- flags (ints, in d_ws, zeroed each launch) ----------------
#define F_HCNT(F, li)     (F)[(li)]
#define F_XWCON(F, li)    (F)[2 + (li)]
#define F_HDONE(F, li, p) (F)[4 + (li) * PP + (p)]
#define F_XWRDY(F, li, c) (F)[16 + (li) * 128 + (c)]

__device__ __forceinline__ int aload(int* p) {
  return __hip_atomic_load(p, __ATOMIC_RELAXED, __HIP_MEMORY_SCOPE_AGENT);
}
__device__ __forceinline__ void arel(int* p, int v) {
  __hip_atomic_store(p, v, __ATOMIC_RELEASE, __HIP_MEMORY_SCOPE_AGENT);
}
__device__ __forceinline__ void acq_fence() {
  __builtin_amdgcn_fence(__ATOMIC_ACQUIRE, "agent");
}
__device__ __forceinline__ void spin_ge(int* p, int tgt) {
  unsigned n = 0;
  while (aload(p) < tgt) {
    __builtin_amdgcn_s_sleep(1);
    if (++n > 20000000u) return;  // hang guard; result will fail visibly
  }
}

// ---------------- init: WT/BV in UNIT-major row order (r = 4u+g) ----------------
__global__ void lstm_init(const float* __restrict__ Wih1, const float* __restrict__ bih1,
                          const float* __restrict__ bhh1, const float* __restrict__ Wih2,
                          const float* __restrict__ bih2, const float* __restrict__ bhh2,
                          float* __restrict__ WT, float* __restrict__ BV) {
  int idx = blockIdx.x * blockDim.x + threadIdx.x;
  int stride = gridDim.x * blockDim.x;
  for (int i = idx; i < 2 * HDIM * RPAD; i += stride) {
    int li = i / (HDIM * RPAD);
    int rem = i - li * HDIM * RPAD;
    int j = rem / RPAD, r = rem - j * RPAD;
    const float* W = li ? Wih2 : Wih1;
    if (r < GDIM) {
      int u = r >> 2, g = r & 3;
      WT[i] = W[(size_t)(g * HDIM + u) * HDIM + j];
    } else {
      WT[i] = 0.f;
    }
  }
  for (int i = idx; i < 2 * RPAD; i += stride) {
    int li = i >> 10, r = i & 1023;
    const float* bi = li ? bih2 : bih1;
    const float* bh = li ? bhh2 : bhh1;
    if (r < GDIM) {
      int u = r >> 2, g = r & 3;
      BV[i] = bi[g * HDIM + u] + bh[g * HDIM + u];
    } else {
      BV[i] = 0.f;
    }
  }
}

// ---------------- main persistent kernel ----------------
// blocks 0..2 : recurrent layer L on ONE CU, 512 threads (2 waves/SIMD).
//   Thread t owns unit-major rows 2t, 2t+1; unit u's 4 gates on adjacent
//   lanes 2u/2u+1 -> gate exchange = 1 ds_swizzle lane^1.
//   Weights fully CU-resident fp16: 20 VGPR + 32 AGPR + 12 LDS quads/thread.
//   AGPR tier consumed via FUSED non-volatile asm blocks (reads+dots in one
//   block -> temps die at block end -> no scratch spill; R15's volatile-ARD
//   version let hoisted temps spill at the 128-reg cap).
// blocks 3..10: projection WGs (xw rings for layers 1,2), chunk protocol.
__global__ void __launch_bounds__(NTH) lstm_main(
    const float* __restrict__ x, const float* __restrict__ Wih0,
    const float* __restrict__ bih0, const float* __restrict__ bhh0,
    const float* __restrict__ Whh0, const float* __restrict__ Whh1,
    const float* __restrict__ Whh2, const float* __restrict__ Wl,
    const float* __restrict__ bl, int* __restrict__ F,
    const float* __restrict__ WT, const float* __restrict__ BV,
    float* __restrict__ hRing, float* __restrict__ xwRing,
    float* __restrict__ out, int T) {
  __shared__ __align__(16) char smem[SMEM_BYTES];
  const int tid = threadIdx.x;
  const int bid = blockIdx.x;
  const int NC = T / CH;

  if (bid < 3) {
    // ================= recurrent layer =================
    const int L = bid;
    const int t = tid;
    const bool tok = (t < 500);
    const int u = t >> 1;
    const int rlo = 2 * t, rhi = 2 * t + 1;  // unit-major rows

    const float* Whh = (L == 0) ? Whh0 : (L == 1) ? Whh1 : Whh2;
    const float* rpL =
        tok ? (Whh + (size_t)((rlo & 3) * HDIM + (rlo >> 2)) * HDIM) : (const float*)nullptr;
    const float* rpH =
        tok ? (Whh + (size_t)((rhi & 3) * HDIM + (rhi >> 2)) * HDIM) : (const float*)nullptr;

    // ---- VGPR tier: k = 0..9 (named) ----
    uint4 wL0, wL1, wL2, wL3, wL4, wL5, wL6, wL7, wL8, wL9;
    uint4 wH0, wH1, wH2, wH3, wH4, wH5, wH6, wH7, wH8, wH9;
#define IVK(k) wL##k = pack8q(rpL, (k) * 8); wH##k = pack8q(rpH, (k) * 8);
    IVK(0) IVK(1) IVK(2) IVK(3) IVK(4) IVK(5) IVK(6) IVK(7) IVK(8) IVK(9)

    // ---- AGPR tier: k = 10..25 (128 named acc dwords, hard "a") ----
#define DECLA(k)                                                       \
  uint32_t aL##k##_0, aL##k##_1, aL##k##_2, aL##k##_3, aH##k##_0,      \
      aH##k##_1, aH##k##_2, aH##k##_3;
    DECLA(10) DECLA(11) DECLA(12) DECLA(13) DECLA(14) DECLA(15) DECLA(16)
    DECLA(17) DECLA(18) DECLA(19) DECLA(20) DECLA(21) DECLA(22) DECLA(23)
    DECLA(24) DECLA(25)
#define IAK(k)                                                          \
  {                                                                     \
    uint4 q = pack8q(rpL, (k) * 8);                                     \
    AWR(aL##k##_0, q.x); AWR(aL##k##_1, q.y);                           \
    AWR(aL##k##_2, q.z); AWR(aL##k##_3, q.w);                           \
    q = pack8q(rpH, (k) * 8);                                           \
    AWR(aH##k##_0, q.x); AWR(aH##k##_1, q.y);                           \
    AWR(aH##k##_2, q.z); AWR(aH##k##_3, q.w);                           \
  }
    IAK(10) IAK(11) IAK(12) IAK(13) IAK(14) IAK(15) IAK(16) IAK(17)
    IAK(18) IAK(19) IAK(20) IAK(21) IAK(22) IAK(23) IAK(24) IAK(25)

    // ---- LDS tier: k = 26..31, slot ((k-26)*2+row)*NTH + tid ----
    for (int k = 26; k < 32; ++k) {
      *(uint4*)(smem + (size_t)(((k - 26) * 2 + 0) * NTH + tid) * 16) =
          pack8q(rpL, k * 8);
      *(uint4*)(smem + (size_t)(((k - 26) * 2 + 1) * NTH + tid) * 16) =
          pack8q(rpH, k * 8);
    }

    // L0 input-projection scalars (2 rows)
    float w0lo = 0.f, b0lo = 0.f, w0hi = 0.f, b0hi = 0.f;
    if (L == 0 && tok) {
      int ilo = (rlo & 3) * HDIM + (rlo >> 2);
      int ihi = (rhi & 3) * HDIM + (rhi >> 2);
      w0lo = Wih0[ilo]; b0lo = bih0[ilo] + bhh0[ilo];
      w0hi = Wih0[ihi]; b0hi = bih0[ihi] + bhh0[ihi];
    }

    // zero both h parities (incl. pad 250..255)
    if (tid < 128) ((uint2*)(smem + HB_BASE))[tid] = make_uint2(0u, 0u);
    __syncthreads();

    const float* xwBase = xwRing + (size_t)(L > 0 ? L - 1 : 0) * XRING * CH * RPAD;
    float* hBase = hRing + (size_t)L * HRING * CH * HDIM;
    float c_st = 0.f, h_last = 0.f;

#pragma unroll 1
    for (int tt = 0; tt < T; ++tt) {
      const int tc = tt & (CH - 1);
      const int c = tt >> 6;
      const int p = tt & 1, ns = p ^ 1;
      if (tc == 0) {  // chunk boundary: input ready / ring backpressure
        if (tid == 0) {
          if (L > 0) spin_ge(&F_XWRDY(F, L - 1, c), 1);
          if (L < 2 && c >= HRING)
            spin_ge(&F_HDONE(F, L, (c - HRING) % PP), c - HRING + 1);
          acq_fence();
        }
        __syncthreads();
      }

      // gate inputs (coalesced float2 in unit-major order)
      float xwlo, xwhi;
      if (L == 0) {
        float xt = x[tt];
        xwlo = fmaf(xt, w0lo, b0lo);
        xwhi = fmaf(xt, w0hi, b0hi);
      } else {
        const float* xp = xwBase + (size_t)(c & (XRING - 1)) * CH * RPAD +
                          (size_t)tc * RPAD;
        const float2 xv = *(const float2*)(xp + 2 * t);
        xwlo = xv.x; xwhi = xv.y;
      }

      const uint4* hb = (const uint4*)(smem + HB_BASE + p * 512);
      // split accumulators (2 per row) to halve the dependent fdot2 chain
      float alo0 = 0.f, alo1 = 0.f, ahi0 = 0.f, ahi1 = 0.f;

#define FD4(W_, H_, A_)                \
  A_ = fdot2u((W_).x, (H_).x, A_);     \
  A_ = fdot2u((W_).y, (H_).y, A_);     \
  A_ = fdot2u((W_).z, (H_).z, A_);     \
  A_ = fdot2u((W_).w, (H_).w, A_);
#define DV(k, AL, AH)                   \
  {                                     \
    const uint4 hq = hb[k];             \
    FD4(wL##k, hq, AL)                  \
    FD4(wH##k, hq, AH)                  \
  }
// fused AGPR-read + dot block: non-volatile, temps die inside the block
#define AQ(P, k, A_)                                                      \
  asm("v_accvgpr_read_b32 %1, %5\n\t"                                     \
      "v_accvgpr_read_b32 %2, %6\n\t"                                     \
      "v_accvgpr_read_b32 %3, %7\n\t"                                     \
      "v_accvgpr_read_b32 %4, %8\n\t"                                     \
      "v_dot2_f32_f16 %0, %1, %9, %0\n\t"                                 \
      "v_dot2_f32_f16 %0, %2, %10, %0\n\t"                                \
      "v_dot2_f32_f16 %0, %3, %11, %0\n\t"                                \
      "v_dot2_f32_f16 %0, %4, %12, %0"                                    \
      : "+v"(A_), "=&v"(q0_), "=&v"(q1_), "=&v"(q2_), "=&v"(q3_)          \
      : "a"(a##P##k##_0), "a"(a##P##k##_1), "a"(a##P##k##_2),             \
        "a"(a##P##k##_3), "v"(hq.x), "v"(hq.y), "v"(hq.z), "v"(hq.w))
#define DA(k, AL, AH)                   \
  {                                     \
    const uint4 hq = hb[k];             \
    uint32_t q0_, q1_, q2_, q3_;        \
    AQ(L, k, AL);                       \
    AQ(H, k, AH);                       \
  }
#define DLK(k, AL, AH)                                                         \
  {                                                                            \
    const uint4 hq = hb[k];                                                    \
    uint4 q0 = *(const uint4*)(smem +                                          \
        (size_t)((((k) - 26) * 2 + 0) * NTH + tid) * 16);                      \
    FD4(q0, hq, AL)                                                            \
    uint4 q1 = *(const uint4*)(smem +                                          \
        (size_t)((((k) - 26) * 2 + 1) * NTH + tid) * 16);                      \
    FD4(q1, hq, AH)                                                            \
  }

      DV(0, alo0, ahi0) DV(1, alo1, ahi1) DV(2, alo0, ahi0) DV(3, alo1, ahi1)
      DV(4, alo0, ahi0) DV(5, alo1, ahi1) DV(6, alo0, ahi0) DV(7, alo1, ahi1)
      DV(8, alo0, ahi0) DV(9, alo1, ahi1)
      DA(10, alo0, ahi0) DA(11, alo1, ahi1) DA(12, alo0, ahi0)
      DA(13, alo1, ahi1) DA(14, alo0, ahi0) DA(15, alo1, ahi1)
      DA(16, alo0, ahi0) DA(17, alo1, ahi1) DA(18, alo0, ahi0)
      DA(19, alo1, ahi1) DA(20, alo0, ahi0) DA(21, alo1, ahi1)
      DA(22, alo0, ahi0) DA(23, alo1, ahi1) DA(24, alo0, ahi0)
      DA(25, alo1, ahi1)
      DLK(26, alo0, ahi0) DLK(27, alo1, ahi1) DLK(28, alo0, ahi0)
      DLK(29, alo1, ahi1) DLK(30, alo0, ahi0) DLK(31, alo1, ahi1)

      float alo = (alo0 + alo1) + xwlo;
      float ahi = (ahi0 + ahi1) + xwhi;

      // gate exchange between the unit's two adjacent lanes (xor 1)
      const float slo = swz<0x041F>(alo);
      const float shi = swz<0x041F>(ahi);
      const bool even = !(t & 1);
      const float gi = even ? alo : slo;
      const float gf = even ? ahi : shi;
      const float gg = even ? slo : alo;
      const float go = even ? shi : ahi;

      const float ii = sigm(gi), ff = sigm(gf), tg = tanh_(gg), oo = sigm(go);
      c_st = ff * c_st + ii * tg;
      const float hn = oo * tanh_(c_st);
      h_last = hn;

      if (tok && even) {
        *(_Float16*)(smem + HB_BASE + ns * 512 + u * 2) = (_Float16)hn;
        if (L < 2)
          hBase[(size_t)(c & (HRING - 1)) * CH * HDIM + (size_t)tc * HDIM + u] = hn;
      }

      if (tc == CH - 1) {  // chunk end: drain stores, publish flags
        asm volatile("s_waitcnt vmcnt(0)" ::: "memory");
        __syncthreads();
        if (tid == 0) {
          if (L < 2) arel(&F_HCNT(F, L), c + 1);
          if (L > 0) arel(&F_XWCON(F, L - 1), c + 1);
        }
        __syncthreads();
      } else {
        step_barrier();  // lgkm-only: h parity write visible to next step
      }
    }

    if (L == 2) {  // final linear on h2[T-1]
      float* red = (float*)(smem + RED_BASE);
      if (tok && !(t & 1)) red[u] = h_last * Wl[u];
      __syncthreads();
      if (tid == 0) {
        float s = bl[0];
        for (int j = 0; j < HDIM; ++j) s += red[j];
        out[0] = s;
      }
    }
  } else {
    // ================= projection role (512 threads, 8 waves) =================
    const int li = (bid - 3) / PP;
    const int p = (bid - 3) % PP;
    float* ldsH = (float*)smem;  // [64][257] f32
    const int lane = tid & 63, wid = tid >> 6;
    const float* WTl = WT + (size_t)li * HDIM * RPAD;
    const float* BVl = BV + (size_t)li * RPAD;

    for (int c = p; c < NC; c += PP) {
      if (tid == 0) {
        spin_ge(&F_HCNT(F, li), c + 1);
        if (c >= XRING) spin_ge(&F_XWCON(F, li), c - XRING + 1);
        acq_fence();
      }
      __syncthreads();
      const float* hsrc = hRing + (size_t)li * HRING * CH * HDIM +
                          (size_t)(c & (HRING - 1)) * CH * HDIM;
      for (int t2 = wid; t2 < CH; t2 += 8)
        for (int j = lane; j < HDIM; j += 64)
          ldsH[t2 * 257 + j] = hsrc[t2 * HDIM + j];
      __syncthreads();
      if (tid == 0) arel(&F_HDONE(F, li, p), c + 1);

      float* xdst = xwRing + (size_t)li * XRING * CH * RPAD +
                    (size_t)(c & (XRING - 1)) * CH * RPAD;
      const int rb0 = wid * 128;  // 8 waves x 128 rows
      for (int grpq = 0; grpq < 16; ++grpq) {
        const int rb = rb0 + grpq * 8;
        float acc[8];
#pragma unroll
        for (int uq = 0; uq < 8; ++uq) acc[uq] = 0.f;
        const float* wp = WTl + rb;
        float4 wa4 = *(const float4*)(wp);
        float4 wb4 = *(const float4*)(wp + 4);
        for (int j = 0; j < HDIM; ++j) {
          int jn = (j + 1 < HDIM) ? j + 1 : HDIM - 1;
          float4 na = *(const float4*)(wp + (size_t)jn * RPAD);
          float4 nb = *(const float4*)(wp + (size_t)jn * RPAD + 4);
          float hj = ldsH[lane * 257 + j];
          acc[0] = fmaf(wa4.x, hj, acc[0]); acc[1] = fmaf(wa4.y, hj, acc[1]);
          acc[2] = fmaf(wa4.z, hj, acc[2]); acc[3] = fmaf(wa4.w, hj, acc[3]);
          acc[4] = fmaf(wb4.x, hj, acc[4]); acc[5] = fmaf(wb4.y, hj, acc[5]);
          acc[6] = fmaf(wb4.z, hj, acc[6]); acc[7] = fmaf(wb4.w, hj, acc[7]);
          wa4 = na; wb4 = nb;
        }
#pragma unroll
        for (int uq = 0; uq < 8; ++uq) {
          int r = rb + uq;
          if (r < GDIM) xdst[(size_t)lane * RPAD + r] = acc[uq] + BVl[r];
        }
      }
      __syncthreads();
      if (tid == 0) arel(&F_XWRDY(F, li, c), 1);
    }
  }
}

// ---------------- launch ----------------
extern "C" void kernel_launch(void* const* d_in, const int* in_sizes, int n_in,
                              void* d_out, int out_size, void* d_ws, size_t ws_size,
                              hipStream_t stream) {
  const float* x    = (const float*)d_in[0];
  const float* Wih0 = (const float*)d_in[1];
  const float* Whh0 = (const float*)d_in[2];
  const float* bih0 = (const float*)d_in[3];
  const float* bhh0 = (const float*)d_in[4];
  const float* Wih1 = (const float*)d_in[5];
  const float* Whh1 = (const float*)d_in[6];
  const float* bih1 = (const float*)d_in[7];
  const float* bhh1 = (const float*)d_in[8];
  const float* Wih2 = (const float*)d_in[9];
  const float* Whh2 = (const float*)d_in[10];
  const float* bih2 = (const float*)d_in[11];
  const float* bhh2 = (const float*)d_in[12];
  const float* Wl   = (const float*)d_in[13];
  const float* bl   = (const float*)d_in[14];
  const int T = in_sizes[0];

  char* ws = (char*)d_ws;
  int*   F   = (int*)ws;                          // 4,096 B flags
  float* WT  = (float*)(ws + 4096);               // 2,048,000 B
  float* BV  = (float*)(ws + 2052096);            // 8,192 B
  float* hR  = (float*)(ws + 2060288);            // 2*2*64*250*4 = 256,000 B
  float* xwR = (float*)(ws + 2316288);            // 2*2*64*1024*4 = 1,048,576 B
                                                  // end: 3,364,864 B

  hipMemsetAsync(F, 0, 4096, stream);  // reset protocol state every replay
  lstm_init<<<256, 256, 0, stream>>>(Wih1, bih1, bhh1, Wih2, bih2, bhh2, WT, BV);
  lstm_main<<<3 + 2 * PP, NTH, 0, stream>>>(
      x, Wih0, bih0, bhh0, Whh0, Whh1, Whh2, Wl, bl, F, WT, BV, hR, xwR,
      (float*)d_out, T);
}

// Round 17
// 20776.167 us; speedup vs baseline: 2.2980x; 1.9478x over previous
//
#include <hip/hip_runtime.h>
#include <cstdint>

// ---------------- configuration ----------------
#define HDIM 250          // hidden size
#define GDIM 1000         // 4*H gate rows
#define CH   64           // chunk length (steps) for inter-WG handoff
#define PP   4            // projection WGs per layer
#define HRING 4           // h ring depth (chunks)
#define XRING 4           // xw ring depth (chunks)
#define RPAD 1024         // padded gate-row dimension
#define NTH  1024         // 16 waves = 4 waves/SIMD (R6: proven best TLP)

// rec-role weight tiers per thread (4 gate rows x 8 col-quads = 32 quads):
//   k 0..1        VGPR (8 quads, 32 regs; hard budget is 64 at NTH=1024)
//   k 2..5 (r<3), k 2..4 (r=3)  AGPR (15 quads, 60 acc regs, hard "a")
//   k 6..7 (r<3), k 5..7 (r=3)  LDS  (9 quads, 147456 B)
#define LQ_N 9
#define LDSW_BYTES (LQ_N * NTH * 16)        // 147456
#define HSEG 144                            // skewed h segment stride
#define HBUF (4 * HSEG)                     // 576 B per parity
#define HB_BASE LDSW_BYTES                  // 147456
#define RED_BASE (HB_BASE + 2 * HBUF)       // 148608
#define SMEM_BYTES (RED_BASE + 1024)        // 149632 <= 163840 (proj needs 65792)

typedef _Float16 f16x2 __attribute__((ext_vector_type(2)));

__device__ __forceinline__ float fdot2u(uint32_t w, uint32_t h, float acc) {
#if defined(__has_builtin) && __has_builtin(__builtin_amdgcn_fdot2)
  return __builtin_amdgcn_fdot2(__builtin_bit_cast(f16x2, w),
                                __builtin_bit_cast(f16x2, h), acc, false);
#else
  f16x2 wv = __builtin_bit_cast(f16x2, w), hv = __builtin_bit_cast(f16x2, h);
  return acc + (float)wv[0] * (float)hv[0] + (float)wv[1] * (float)hv[1];
#endif
}

__device__ __forceinline__ uint32_t pkh2(float a, float b) {
  f16x2 p; p[0] = (_Float16)a; p[1] = (_Float16)b;
  return __builtin_bit_cast(uint32_t, p);
}

// pack 8 consecutive f32 weights (zero beyond HDIM / null row) into 4x fp16x2
__device__ __forceinline__ uint4 pack8q(const float* rp, int c0) {
  float c[8];
#pragma unroll
  for (int u = 0; u < 8; ++u) {
    int col = c0 + u;
    c[u] = (rp && col < HDIM) ? rp[col] : 0.f;
  }
  uint4 r;
  r.x = pkh2(c[0], c[1]); r.y = pkh2(c[2], c[3]);
  r.z = pkh2(c[4], c[5]); r.w = pkh2(c[6], c[7]);
  return r;
}

__device__ __forceinline__ float rcpf_(float x) {
#if defined(__has_builtin) && __has_builtin(__builtin_amdgcn_rcpf)
  return __builtin_amdgcn_rcpf(x);
#else
  return 1.f / x;
#endif
}
__device__ __forceinline__ float sigm(float x) {
  return rcpf_(1.f + exp2f(-1.44269504088896341f * x));
}
__device__ __forceinline__ float tanh_(float x) {
  float e = exp2f(2.88539008177792681f * x);
  return 1.f - 2.f * rcpf_(e + 1.f);
}

// DPP quad_perm: 0xB1 = lane^1, 0x4E = lane^2 (within 4-lane quads)
template <int CTRL>
__device__ __forceinline__ float dppq(float v) {
  return __builtin_bit_cast(
      float, __builtin_amdgcn_update_dpp(0, __builtin_bit_cast(int, v), CTRL,
                                         0xF, 0xF, true));
}

// lgkmcnt-only barrier: keeps global prefetches in flight across steps
__device__ __forceinline__ void step_barrier() {
  asm volatile("s_waitcnt lgkmcnt(0)\n\ts_barrier" ::: "memory");
}

#define AWR(dst, src) \
  asm volatile("v_accvgpr_write_b32 %0, %1" : "=a"(dst) : "v"(src))

// ---------------- flags (in d_ws, zeroed each launch) ----------------
#define F_HCNT(F, li)     (F)[(li)]
#define F_XWCON(F, li)    (F)[2 + (li)]
#define F_HDONE(F, li, p) (F)[4 + (li) * PP + (p)]
#define F_XWRDY(F, li, c) (F)[16 + (li) * 128 + (c)]

__device__ __forceinline__ int aload(int* p) {
  return __hip_atomic_load(p, __ATOMIC_RELAXED, __HIP_MEMORY_SCOPE_AGENT);
}
__device__ __forceinline__ void arel(int* p, int v) {
  __hip_atomic_store(p, v, __ATOMIC_RELEASE, __HIP_MEMORY_SCOPE_AGENT);
}
__device__ __forceinline__ void acq_fence() {
  __builtin_amdgcn_fence(__ATOMIC_ACQUIRE, "agent");
}
__device__ __forceinline__ void spin_ge(int* p, int tgt) {
  unsigned n = 0;
  while (aload(p) < tgt) {
    __builtin_amdgcn_s_sleep(1);
    if (++n > 100000000u) return;  // hang guard; result will fail visibly
  }
}

// ---------------- init: transpose Wih1/2 -> WT[li][j][RPAD], biases ----------------
__global__ void lstm_init(const float* __restrict__ Wih1, const float* __restrict__ bih1,
                          const float* __restrict__ bhh1, const float* __restrict__ Wih2,
                          const float* __restrict__ bih2, const float* __restrict__ bhh2,
                          float* __restrict__ WT, float* __restrict__ BV) {
  int idx = blockIdx.x * blockDim.x + threadIdx.x;
  int stride = gridDim.x * blockDim.x;
  for (int i = idx; i < 2 * HDIM * RPAD; i += stride) {
    int li = i / (HDIM * RPAD);
    int rem = i - li * HDIM * RPAD;
    int j = rem / RPAD, r = rem - j * RPAD;
    const float* W = li ? Wih2 : Wih1;
    WT[i] = (r < GDIM) ? W[r * HDIM + j] : 0.f;
  }
  for (int i = idx; i < 2 * RPAD; i += stride) {
    int li = i >> 10, r = i & 1023;
    const float* bi = li ? bih2 : bih1;
    const float* bh = li ? bhh2 : bhh1;
    BV[i] = (r < GDIM) ? bi[r] + bh[r] : 0.f;
  }
}

// ---------------- main persistent kernel ----------------
// blocks 0..2  : recurrent layer L on ONE CU (R6 skeleton: 1024 threads = 256
//   unit-groups x 4 col-slice lanes; group owns unit u = tid>>2, all 4 gates;
//   lane slice = 64 cols; DPP butterfly reduce; redundant LSTM update).
//   Weights fully CU-resident: 8 VGPR + 15 AGPR + 9 LDS quads per thread.
// blocks 3..10 : projection WGs (xw rings for layers 1,2), chunk protocol.
__global__ void __launch_bounds__(NTH) lstm_main(
    const float* __restrict__ x, const float* __restrict__ Wih0,
    const float* __restrict__ bih0, const float* __restrict__ bhh0,
    const float* __restrict__ Whh0, const float* __restrict__ Whh1,
    const float* __restrict__ Whh2, const float* __restrict__ Wl,
    const float* __restrict__ bl, int* __restrict__ F,
    const float* __restrict__ WT, const float* __restrict__ BV,
    float* __restrict__ hRing, float* __restrict__ xwRing,
    float* __restrict__ out, int T) {
  __shared__ __align__(16) char smem[SMEM_BYTES];
  const int tid = threadIdx.x;
  const int bid = blockIdx.x;
  const int NC = T / CH;

  if (bid < 3) {
    // ================= recurrent role =================
    const int L = bid;
    const int u = tid >> 2, sl = tid & 3;
    const bool uok = (u < HDIM);
    const int r_abs = sl * HDIM + u;  // this lane's xw gate-row

    const float* Whh = (L == 0) ? Whh0 : (L == 1) ? Whh1 : Whh2;
    char* lw = smem + tid * 16;
#define LWADDR(s) (lw + (size_t)(s) * (NTH * 16))
#define ROWP(r) (uok ? (Whh + ((size_t)(r) * HDIM + u) * HDIM) : (const float*)nullptr)

    // ---- VGPR tier: rows 0..3, k = 0,1 (8 named quads) ----
    uint4 w00, w01, w10, w11, w20, w21, w30, w31;
    w00 = pack8q(ROWP(0), sl * 64 + 0); w01 = pack8q(ROWP(0), sl * 64 + 8);
    w10 = pack8q(ROWP(1), sl * 64 + 0); w11 = pack8q(ROWP(1), sl * 64 + 8);
    w20 = pack8q(ROWP(2), sl * 64 + 0); w21 = pack8q(ROWP(2), sl * 64 + 8);
    w30 = pack8q(ROWP(3), sl * 64 + 0); w31 = pack8q(ROWP(3), sl * 64 + 8);

    // ---- AGPR tier: 15 quads = 60 named acc dwords (hard "a") ----
#define DECLAQ(r, k) \
  uint32_t ag##r##_##k##_0, ag##r##_##k##_1, ag##r##_##k##_2, ag##r##_##k##_3;
    DECLAQ(0, 2) DECLAQ(0, 3) DECLAQ(0, 4) DECLAQ(0, 5)
    DECLAQ(1, 2) DECLAQ(1, 3) DECLAQ(1, 4) DECLAQ(1, 5)
    DECLAQ(2, 2) DECLAQ(2, 3) DECLAQ(2, 4) DECLAQ(2, 5)
    DECLAQ(3, 2) DECLAQ(3, 3) DECLAQ(3, 4)
#define IAQ(r, k)                                               \
  {                                                             \
    uint4 q = pack8q(ROWP(r), sl * 64 + (k) * 8);               \
    AWR(ag##r##_##k##_0, q.x); AWR(ag##r##_##k##_1, q.y);       \
    AWR(ag##r##_##k##_2, q.z); AWR(ag##r##_##k##_3, q.w);       \
  }
    IAQ(0, 2) IAQ(0, 3) IAQ(0, 4) IAQ(0, 5)
    IAQ(1, 2) IAQ(1, 3) IAQ(1, 4) IAQ(1, 5)
    IAQ(2, 2) IAQ(2, 3) IAQ(2, 4) IAQ(2, 5)
    IAQ(3, 2) IAQ(3, 3) IAQ(3, 4)

    // ---- LDS tier: 9 slots ----
    // s: 0=(r0,k6) 1=(r0,k7) 2=(r1,k6) 3=(r1,k7) 4=(r2,k6) 5=(r2,k7)
    //    6=(r3,k5) 7=(r3,k6) 8=(r3,k7)
    *(uint4*)LWADDR(0) = pack8q(ROWP(0), sl * 64 + 48);
    *(uint4*)LWADDR(1) = pack8q(ROWP(0), sl * 64 + 56);
    *(uint4*)LWADDR(2) = pack8q(ROWP(1), sl * 64 + 48);
    *(uint4*)LWADDR(3) = pack8q(ROWP(1), sl * 64 + 56);
    *(uint4*)LWADDR(4) = pack8q(ROWP(2), sl * 64 + 48);
    *(uint4*)LWADDR(5) = pack8q(ROWP(2), sl * 64 + 56);
    *(uint4*)LWADDR(6) = pack8q(ROWP(3), sl * 64 + 40);
    *(uint4*)LWADDR(7) = pack8q(ROWP(3), sl * 64 + 48);
    *(uint4*)LWADDR(8) = pack8q(ROWP(3), sl * 64 + 56);

    // L0 per-lane input-projection scalars
    float w0_ = 0.f, b0_ = 0.f;
    if (L == 0 && uok) {
      w0_ = Wih0[r_abs];
      b0_ = bih0[r_abs] + bhh0[r_abs];
    }

    // zero both h buffers (incl. padded cols 250..255)
    for (int i = tid; i < (2 * HBUF) / 4; i += NTH)
      *(uint32_t*)(smem + HB_BASE + 4 * i) = 0u;
    __syncthreads();

    const float* xwBase = xwRing + (size_t)(L > 0 ? L - 1 : 0) * XRING * CH * RPAD;
    float* hBase = hRing + (size_t)L * HRING * CH * HDIM;
    float c_st = 0.f, h_last = 0.f;

    for (int tt = 0; tt < T; ++tt) {
      const int tc = tt & (CH - 1);
      const int c = tt >> 6;
      if (tc == 0) {  // chunk boundary: wait for inputs / ring backpressure
        if (tid == 0) {
          if (L > 0) spin_ge(&F_XWRDY(F, L - 1, c), 1);
          if (L < 2 && c >= HRING) {
            int cc = c - HRING;
            spin_ge(&F_HDONE(F, L, cc % PP), cc + 1);
          }
          acq_fence();
        }
        __syncthreads();
      }

      // this lane's gate input (VMEM issued early, consumed after the dot)
      float xw = 0.f;
      if (uok) {
        if (L == 0) {
          xw = fmaf(x[tt], w0_, b0_);
        } else {
          const float* xp = xwBase + (size_t)(c & (XRING - 1)) * CH * RPAD +
                            (size_t)tc * RPAD;
          xw = xp[r_abs];
        }
      }

      // dot: 4 gate rows x 64-col slice; fp16 dot2, f32 accumulate
      const char* hb = smem + HB_BASE + (tt & 1) * HBUF + sl * HSEG;
      float a0 = 0.f, a1 = 0.f, a2 = 0.f, a3 = 0.f;

#define FD4(W_, H_, A_)                \
  A_ = fdot2u((W_).x, (H_).x, A_);     \
  A_ = fdot2u((W_).y, (H_).y, A_);     \
  A_ = fdot2u((W_).z, (H_).z, A_);     \
  A_ = fdot2u((W_).w, (H_).w, A_);
// fused AGPR-read + dot block: non-volatile, temps die inside the block
#define AQ(r, k, A_)                                                      \
  asm("v_accvgpr_read_b32 %1, %5\n\t"                                     \
      "v_accvgpr_read_b32 %2, %6\n\t"                                     \
      "v_accvgpr_read_b32 %3, %7\n\t"                                     \
      "v_accvgpr_read_b32 %4, %8\n\t"                                     \
      "v_dot2_f32_f16 %0, %1, %9, %0\n\t"                                 \
      "v_dot2_f32_f16 %0, %2, %10, %0\n\t"                                \
      "v_dot2_f32_f16 %0, %3, %11, %0\n\t"                                \
      "v_dot2_f32_f16 %0, %4, %12, %0"                                    \
      : "+v"(A_), "=&v"(q0_), "=&v"(q1_), "=&v"(q2_), "=&v"(q3_)          \
      : "a"(ag##r##_##k##_0), "a"(ag##r##_##k##_1), "a"(ag##r##_##k##_2), \
        "a"(ag##r##_##k##_3), "v"(hq.x), "v"(hq.y), "v"(hq.z), "v"(hq.w))

      {  // k = 0 (VGPR)
        const uint4 hq = *(const uint4*)(hb + 0);
        FD4(w00, hq, a0) FD4(w10, hq, a1) FD4(w20, hq, a2) FD4(w30, hq, a3)
      }
      {  // k = 1 (VGPR)
        const uint4 hq = *(const uint4*)(hb + 16);
        FD4(w01, hq, a0) FD4(w11, hq, a1) FD4(w21, hq, a2) FD4(w31, hq, a3)
      }
      {  // k = 2 (AGPR)
        const uint4 hq = *(const uint4*)(hb + 32);
        uint32_t q0_, q1_, q2_, q3_;
        AQ(0, 2, a0); AQ(1, 2, a1); AQ(2, 2, a2); AQ(3, 2, a3);
      }
      {  // k = 3 (AGPR)
        const uint4 hq = *(const uint4*)(hb + 48);
        uint32_t q0_, q1_, q2_, q3_;
        AQ(0, 3, a0); AQ(1, 3, a1); AQ(2, 3, a2); AQ(3, 3, a3);
      }
      {  // k = 4 (AGPR)
        const uint4 hq = *(const uint4*)(hb + 64);
        uint32_t q0_, q1_, q2_, q3_;
        AQ(0, 4, a0); AQ(1, 4, a1); AQ(2, 4, a2); AQ(3, 4, a3);
      }
      {  // k = 5 (AGPR rows 0-2, LDS row 3)
        const uint4 hq = *(const uint4*)(hb + 80);
        uint32_t q0_, q1_, q2_, q3_;
        AQ(0, 5, a0); AQ(1, 5, a1); AQ(2, 5, a2);
        uint4 t = *(const uint4*)LWADDR(6);
        FD4(t, hq, a3)
      }
      {  // k = 6 (LDS)
        const uint4 hq = *(const uint4*)(hb + 96);
        uint4 t;
        t = *(const uint4*)LWADDR(0); FD4(t, hq, a0)
        t = *(const uint4*)LWADDR(2); FD4(t, hq, a1)
        t = *(const uint4*)LWADDR(4); FD4(t, hq, a2)
        t = *(const uint4*)LWADDR(7); FD4(t, hq, a3)
      }
      {  // k = 7 (LDS)
        const uint4 hq = *(const uint4*)(hb + 112);
        uint4 t;
        t = *(const uint4*)LWADDR(1); FD4(t, hq, a0)
        t = *(const uint4*)LWADDR(3); FD4(t, hq, a1)
        t = *(const uint4*)LWADDR(5); FD4(t, hq, a2)
        t = *(const uint4*)LWADDR(8); FD4(t, hq, a3)
      }

      // add xw into the gate row this lane owns, then butterfly over 4 lanes
      a0 += (sl == 0) ? xw : 0.f;
      a1 += (sl == 1) ? xw : 0.f;
      a2 += (sl == 2) ? xw : 0.f;
      a3 += (sl == 3) ? xw : 0.f;
      a0 += dppq<0xB1>(a0); a0 += dppq<0x4E>(a0);
      a1 += dppq<0xB1>(a1); a1 += dppq<0x4E>(a1);
      a2 += dppq<0xB1>(a2); a2 += dppq<0x4E>(a2);
      a3 += dppq<0xB1>(a3); a3 += dppq<0x4E>(a3);

      // update (all 4 lanes redundantly; consistent deterministic math)
      float ii = sigm(a0), ff = sigm(a1), tg = tanh_(a2), oo = sigm(a3);
      c_st = ff * c_st + ii * tg;
      float hn = oo * tanh_(c_st);
      h_last = hn;

      if (sl == 0 && uok) {
        // fp16 h into next-step buffer (segment u>>6, skewed)
        char* hw = smem + HB_BASE + ((tt + 1) & 1) * HBUF + (u >> 6) * HSEG +
                   (u & 63) * 2;
        *(_Float16*)hw = (_Float16)hn;
        if (L < 2)
          hBase[(size_t)(c & (HRING - 1)) * CH * HDIM + (size_t)tc * HDIM + u] = hn;
      }

      if (tc == CH - 1) {  // chunk end: full barrier then publish
        __syncthreads();
        if (tid == 0) {
          if (L < 2) arel(&F_HCNT(F, L), c + 1);
          if (L > 0) arel(&F_XWCON(F, L - 1), c + 1);
        }
      } else {
        step_barrier();  // h(next) writes visible; lgkm-only
      }
    }

    if (L == 2) {  // final linear on h2[T-1]
      float* red = (float*)(smem + RED_BASE);
      if (sl == 0 && uok) red[u] = h_last;
      __syncthreads();
      if (tid == 0) {
        float s = bl[0];
        for (int j = 0; j < HDIM; ++j) s += red[j] * Wl[j];
        out[0] = s;
      }
    }
  } else {
    // ================= projection role (1024 threads, 16 waves) =================
    const int li = (bid - 3) / PP;
    const int p = (bid - 3) % PP;
    float* ldsH = (float*)smem;  // [64][257] f32
    const int lane = tid & 63, wid = tid >> 6;
    const float* WTl = WT + (size_t)li * HDIM * RPAD;
    const float* BVl = BV + (size_t)li * RPAD;

    for (int c = p; c < NC; c += PP) {
      if (tid == 0) {
        spin_ge(&F_HCNT(F, li), c + 1);
        if (c >= XRING) spin_ge(&F_XWCON(F, li), c - XRING + 1);
        acq_fence();
      }
      __syncthreads();
      const float* hsrc = hRing + (size_t)li * HRING * CH * HDIM +
                          (size_t)(c & (HRING - 1)) * CH * HDIM;
      for (int t = wid; t < CH; t += 16)
        for (int j = lane; j < HDIM; j += 64)
          ldsH[t * 257 + j] = hsrc[t * HDIM + j];
      __syncthreads();
      if (tid == 0) arel(&F_HDONE(F, li, p), c + 1);

      float* xdst = xwRing + (size_t)li * XRING * CH * RPAD +
                    (size_t)(c & (XRING - 1)) * CH * RPAD;
      const int rb0 = wid * 64;  // 16 waves x 64 rows = 1024 padded rows
      for (int grpq = 0; grpq < 8; ++grpq) {
        const int rb = rb0 + grpq * 8;
        float acc[8];
#pragma unroll
        for (int uq = 0; uq < 8; ++uq) acc[uq] = 0.f;
        const float* wp = WTl + rb;
        float4 wa4 = *(const float4*)(wp);
        float4 wb4 = *(const float4*)(wp + 4);
        for (int j = 0; j < HDIM; ++j) {
          int jn = (j + 1 < HDIM) ? j + 1 : HDIM - 1;
          float4 na = *(const float4*)(wp + (size_t)jn * RPAD);
          float4 nb = *(const float4*)(wp + (size_t)jn * RPAD + 4);
          float hj = ldsH[lane * 257 + j];
          acc[0] = fmaf(wa4.x, hj, acc[0]); acc[1] = fmaf(wa4.y, hj, acc[1]);
          acc[2] = fmaf(wa4.z, hj, acc[2]); acc[3] = fmaf(wa4.w, hj, acc[3]);
          acc[4] = fmaf(wb4.x, hj, acc[4]); acc[5] = fmaf(wb4.y, hj, acc[5]);
          acc[6] = fmaf(wb4.z, hj, acc[6]); acc[7] = fmaf(wb4.w, hj, acc[7]);
          wa4 = na; wb4 = nb;
        }
#pragma unroll
        for (int uq = 0; uq < 8; ++uq) {
          int r = rb + uq;
          if (r < GDIM) xdst[(size_t)lane * RPAD + r] = acc[uq] + BVl[r];
        }
      }
      __syncthreads();
      if (tid == 0) arel(&F_XWRDY(F, li, c), 1);
    }
  }
}

// ---------------- launch ----------------
extern "C" void kernel_launch(void* const* d_in, const int* in_sizes, int n_in,
                              void* d_out, int out_size, void* d_ws, size_t ws_size,
                              hipStream_t stream) {
  const float* x    = (const float*)d_in[0];
  const float* Wih0 = (const float*)d_in[1];
  const float* Whh0 = (const float*)d_in[2];
  const float* bih0 = (const float*)d_in[3];
  const float* bhh0 = (const float*)d_in[4];
  const float* Wih1 = (const float*)d_in[5];
  const float* Whh1 = (const float*)d_in[6];
  const float* bih1 = (const float*)d_in[7];
  const float* bhh1 = (const float*)d_in[8];
  const float* Wih2 = (const float*)d_in[9];
  const float* Whh2 = (const float*)d_in[10];
  const float* bih2 = (const float*)d_in[11];
  const float* bhh2 = (const float*)d_in[12];
  const float* Wl   = (const float*)d_in[13];
  const float* bl   = (const float*)d_in[14];
  const int T = in_sizes[0];

  char* ws = (char*)d_ws;
  int*   F   = (int*)ws;                                        // 4096 B flags
  float* WT  = (float*)(ws + 4096);                             // 2,048,000 B
  float* BV  = (float*)(ws + 4096 + 2048000);                   // 8,192 B
  float* hR  = (float*)(ws + 4096 + 2048000 + 8192);            // 512,000 B
  float* xwR = (float*)(ws + 4096 + 2048000 + 8192 + 512000);   // 2,097,152 B

  hipMemsetAsync(F, 0, 4096, stream);  // reset protocol state every replay
  lstm_init<<<256, 256, 0, stream>>>(Wih1, bih1, bhh1, Wih2, bih2, bhh2, WT, BV);
  lstm_main<<<3 + 2 * PP, NTH, 0, stream>>>(
      x, Wih0, bih0, bhh0, Whh0, Whh1, Whh2, Wl, bl, F, WT, BV, hR, xwR,
      (float*)d_out, T);
}

// Round 18
// 20641.586 us; speedup vs baseline: 2.3130x; 1.0065x over previous
//
#include <hip/hip_runtime.h>
#include <cstdint>

// ---------------- configuration ----------------
#define HDIM 250          // hidden size
#define GDIM 1000         // 4*H gate rows
#define CH   64           // chunk length (steps) for inter-WG handoff
#define PP   4            // projection WGs per layer
#define HRING 4           // h ring depth (chunks)
#define XRING 4           // xw ring depth (chunks)
#define RPAD 1024         // padded gate-row dimension
#define NTH  1024         // 16 waves = 4 waves/SIMD (proven best TLP)

// rec-role weight tiers per thread (4 gate rows x 8 col-quads = 32 quads):
//   k 0..1        VGPR (8 quads, 32 regs; budget law: 131072/(2*NTH) = 64)
//   k 2..5 (r<3), k 2..4 (r=3)  AGPR (15 quads, 60 acc regs, hard "a";
//                 64 arch + 60 acc = 124 <= 128 total/wave at 4 waves/SIMD)
//   k 6..7 (r<3), k 5..7 (r=3)  LDS  (9 quads, 147456 B)
#define LQ_N 9
#define LDSW_BYTES (LQ_N * NTH * 16)        // 147456
#define HSEG 144                            // skewed h segment stride
#define HBUF (4 * HSEG)                     // 576 B per parity
#define HB_BASE LDSW_BYTES                  // 147456
#define RED_BASE (HB_BASE + 2 * HBUF)       // 148608
#define SMEM_BYTES (RED_BASE + 1024)        // 149632 <= 163840 (proj needs 65792)

typedef _Float16 f16x2 __attribute__((ext_vector_type(2)));

__device__ __forceinline__ float fdot2u(uint32_t w, uint32_t h, float acc) {
#if defined(__has_builtin) && __has_builtin(__builtin_amdgcn_fdot2)
  return __builtin_amdgcn_fdot2(__builtin_bit_cast(f16x2, w),
                                __builtin_bit_cast(f16x2, h), acc, false);
#else
  f16x2 wv = __builtin_bit_cast(f16x2, w), hv = __builtin_bit_cast(f16x2, h);
  return acc + (float)wv[0] * (float)hv[0] + (float)wv[1] * (float)hv[1];
#endif
}

__device__ __forceinline__ uint32_t pkh2(float a, float b) {
  f16x2 p; p[0] = (_Float16)a; p[1] = (_Float16)b;
  return __builtin_bit_cast(uint32_t, p);
}

// pack 8 consecutive f32 weights (zero beyond HDIM / null row) into 4x fp16x2
__device__ __forceinline__ uint4 pack8q(const float* rp, int c0) {
  float c[8];
#pragma unroll
  for (int u = 0; u < 8; ++u) {
    int col = c0 + u;
    c[u] = (rp && col < HDIM) ? rp[col] : 0.f;
  }
  uint4 r;
  r.x = pkh2(c[0], c[1]); r.y = pkh2(c[2], c[3]);
  r.z = pkh2(c[4], c[5]); r.w = pkh2(c[6], c[7]);
  return r;
}

__device__ __forceinline__ float rcpf_(float x) {
#if defined(__has_builtin) && __has_builtin(__builtin_amdgcn_rcpf)
  return __builtin_amdgcn_rcpf(x);
#else
  return 1.f / x;
#endif
}
__device__ __forceinline__ float sigm(float x) {
  return rcpf_(1.f + exp2f(-1.44269504088896341f * x));
}
__device__ __forceinline__ float tanh_(float x) {
  float e = exp2f(2.88539008177792681f * x);
  return 1.f - 2.f * rcpf_(e + 1.f);
}

// DPP quad_perm: 0xB1 = lane^1, 0x4E = lane^2 (within 4-lane quads)
template <int CTRL>
__device__ __forceinline__ float dppq(float v) {
  return __builtin_bit_cast(
      float, __builtin_amdgcn_update_dpp(0, __builtin_bit_cast(int, v), CTRL,
                                         0xF, 0xF, true));
}

// lgkmcnt-only barrier: keeps global prefetches in flight across steps
__device__ __forceinline__ void step_barrier() {
  asm volatile("s_waitcnt lgkmcnt(0)\n\ts_barrier" ::: "memory");
}

#define AWR(dst, src) \
  asm volatile("v_accvgpr_write_b32 %0, %1" : "=a"(dst) : "v"(src))

// ---------------- flags (in d_ws, zeroed each launch) ----------------
#define F_HCNT(F, li)     (F)[(li)]
#define F_XWCON(F, li)    (F)[2 + (li)]
#define F_HDONE(F, li, p) (F)[4 + (li) * PP + (p)]
#define F_XWRDY(F, li, c) (F)[16 + (li) * 128 + (c)]

__device__ __forceinline__ int aload(int* p) {
  return __hip_atomic_load(p, __ATOMIC_RELAXED, __HIP_MEMORY_SCOPE_AGENT);
}
__device__ __forceinline__ void arel(int* p, int v) {
  __hip_atomic_store(p, v, __ATOMIC_RELEASE, __HIP_MEMORY_SCOPE_AGENT);
}
__device__ __forceinline__ void acq_fence() {
  __builtin_amdgcn_fence(__ATOMIC_ACQUIRE, "agent");
}
__device__ __forceinline__ void spin_ge(int* p, int tgt) {
  unsigned n = 0;
  while (aload(p) < tgt) {
    __builtin_amdgcn_s_sleep(1);
    if (++n > 100000000u) return;  // hang guard; result will fail visibly
  }
}

// ---------------- init: transpose Wih1/2 -> WT[li][j][RPAD], biases ----------------
__global__ void lstm_init(const float* __restrict__ Wih1, const float* __restrict__ bih1,
                          const float* __restrict__ bhh1, const float* __restrict__ Wih2,
                          const float* __restrict__ bih2, const float* __restrict__ bhh2,
                          float* __restrict__ WT, float* __restrict__ BV) {
  int idx = blockIdx.x * blockDim.x + threadIdx.x;
  int stride = gridDim.x * blockDim.x;
  for (int i = idx; i < 2 * HDIM * RPAD; i += stride) {
    int li = i / (HDIM * RPAD);
    int rem = i - li * HDIM * RPAD;
    int j = rem / RPAD, r = rem - j * RPAD;
    const float* W = li ? Wih2 : Wih1;
    WT[i] = (r < GDIM) ? W[r * HDIM + j] : 0.f;
  }
  for (int i = idx; i < 2 * RPAD; i += stride) {
    int li = i >> 10, r = i & 1023;
    const float* bi = li ? bih2 : bih1;
    const float* bh = li ? bhh2 : bhh1;
    BV[i] = (r < GDIM) ? bi[r] + bh[r] : 0.f;
  }
}

// ---------------- main persistent kernel ----------------
// blocks 0..2  : recurrent layer L on ONE CU (1024 threads = 256 unit-groups
//   x 4 col-slice lanes; group owns unit u = tid>>2, all 4 gates; lane slice
//   = 64 cols; DPP butterfly reduce; redundant LSTM update).
//   Weights CU-resident: 8 VGPR + 15 AGPR + 9 LDS quads per thread.
//   hRing handoff in fp16 (h is fp16 in the recurrent path anyway).
// blocks 3..10 : projection WGs (xw rings for layers 1,2), chunk protocol.
__global__ void __launch_bounds__(NTH) lstm_main(
    const float* __restrict__ x, const float* __restrict__ Wih0,
    const float* __restrict__ bih0, const float* __restrict__ bhh0,
    const float* __restrict__ Whh0, const float* __restrict__ Whh1,
    const float* __restrict__ Whh2, const float* __restrict__ Wl,
    const float* __restrict__ bl, int* __restrict__ F,
    const float* __restrict__ WT, const float* __restrict__ BV,
    _Float16* __restrict__ hRing, float* __restrict__ xwRing,
    float* __restrict__ out, int T) {
  __shared__ __align__(16) char smem[SMEM_BYTES];
  const int tid = threadIdx.x;
  const int bid = blockIdx.x;
  const int NC = T / CH;

  if (bid < 3) {
    // ================= recurrent role =================
    const int L = bid;
    const int u = tid >> 2, sl = tid & 3;
    const bool uok = (u < HDIM);
    const int r_abs = sl * HDIM + u;  // this lane's xw gate-row

    const float* Whh = (L == 0) ? Whh0 : (L == 1) ? Whh1 : Whh2;
    char* lw = smem + tid * 16;
#define LWADDR(s) (lw + (size_t)(s) * (NTH * 16))
#define ROWP(r) (uok ? (Whh + ((size_t)(r) * HDIM + u) * HDIM) : (const float*)nullptr)

    // ---- VGPR tier: rows 0..3, k = 0,1 (8 named quads) ----
    uint4 w00, w01, w10, w11, w20, w21, w30, w31;
    w00 = pack8q(ROWP(0), sl * 64 + 0); w01 = pack8q(ROWP(0), sl * 64 + 8);
    w10 = pack8q(ROWP(1), sl * 64 + 0); w11 = pack8q(ROWP(1), sl * 64 + 8);
    w20 = pack8q(ROWP(2), sl * 64 + 0); w21 = pack8q(ROWP(2), sl * 64 + 8);
    w30 = pack8q(ROWP(3), sl * 64 + 0); w31 = pack8q(ROWP(3), sl * 64 + 8);

    // ---- AGPR tier: 15 quads = 60 named acc dwords (hard "a") ----
#define DECLAQ(r, k) \
  uint32_t ag##r##_##k##_0, ag##r##_##k##_1, ag##r##_##k##_2, ag##r##_##k##_3;
    DECLAQ(0, 2) DECLAQ(0, 3) DECLAQ(0, 4) DECLAQ(0, 5)
    DECLAQ(1, 2) DECLAQ(1, 3) DECLAQ(1, 4) DECLAQ(1, 5)
    DECLAQ(2, 2) DECLAQ(2, 3) DECLAQ(2, 4) DECLAQ(2, 5)
    DECLAQ(3, 2) DECLAQ(3, 3) DECLAQ(3, 4)
#define IAQ(r, k)                                               \
  {                                                             \
    uint4 q = pack8q(ROWP(r), sl * 64 + (k) * 8);               \
    AWR(ag##r##_##k##_0, q.x); AWR(ag##r##_##k##_1, q.y);       \
    AWR(ag##r##_##k##_2, q.z); AWR(ag##r##_##k##_3, q.w);       \
  }
    IAQ(0, 2) IAQ(0, 3) IAQ(0, 4) IAQ(0, 5)
    IAQ(1, 2) IAQ(1, 3) IAQ(1, 4) IAQ(1, 5)
    IAQ(2, 2) IAQ(2, 3) IAQ(2, 4) IAQ(2, 5)
    IAQ(3, 2) IAQ(3, 3) IAQ(3, 4)

    // ---- LDS tier: 9 slots ----
    *(uint4*)LWADDR(0) = pack8q(ROWP(0), sl * 64 + 48);
    *(uint4*)LWADDR(1) = pack8q(ROWP(0), sl * 64 + 56);
    *(uint4*)LWADDR(2) = pack8q(ROWP(1), sl * 64 + 48);
    *(uint4*)LWADDR(3) = pack8q(ROWP(1), sl * 64 + 56);
    *(uint4*)LWADDR(4) = pack8q(ROWP(2), sl * 64 + 48);
    *(uint4*)LWADDR(5) = pack8q(ROWP(2), sl * 64 + 56);
    *(uint4*)LWADDR(6) = pack8q(ROWP(3), sl * 64 + 40);
    *(uint4*)LWADDR(7) = pack8q(ROWP(3), sl * 64 + 48);
    *(uint4*)LWADDR(8) = pack8q(ROWP(3), sl * 64 + 56);

    // L0 per-lane input-projection scalars
    float w0_ = 0.f, b0_ = 0.f;
    if (L == 0 && uok) {
      w0_ = Wih0[r_abs];
      b0_ = bih0[r_abs] + bhh0[r_abs];
    }

    // zero both h buffers (incl. padded cols 250..255)
    for (int i = tid; i < (2 * HBUF) / 4; i += NTH)
      *(uint32_t*)(smem + HB_BASE + 4 * i) = 0u;
    __syncthreads();

    const float* xwBase = xwRing + (size_t)(L > 0 ? L - 1 : 0) * XRING * CH * RPAD;
    _Float16* hBase = hRing + (size_t)L * HRING * CH * HDIM;
    const float* xpc = xwBase;  // incremental per-step pointer (L>0)
    float c_st = 0.f, h_last = 0.f;

    for (int tt = 0; tt < T; ++tt) {
      const int tc = tt & (CH - 1);
      const int c = tt >> 6;
      if (tc == 0) {  // chunk boundary: wait for inputs / ring backpressure
        if (tid == 0) {
          if (L > 0) spin_ge(&F_XWRDY(F, L - 1, c), 1);
          if (L < 2 && c >= HRING) {
            int cc = c - HRING;
            spin_ge(&F_HDONE(F, L, cc % PP), cc + 1);
          }
          acq_fence();
        }
        __syncthreads();
        xpc = xwBase + (size_t)(c & (XRING - 1)) * CH * RPAD;
      }

      // this lane's gate input (VMEM issued early, consumed after the dot)
      float xw = 0.f;
      if (uok) {
        if (L == 0)
          xw = fmaf(x[tt], w0_, b0_);
        else
          xw = xpc[r_abs];
      }

      // dot: 4 gate rows x 64-col slice; fp16 dot2, f32 accumulate
      const char* hb = smem + HB_BASE + (tt & 1) * HBUF + sl * HSEG;
      float a0 = 0.f, a1 = 0.f, a2 = 0.f, a3 = 0.f;

#define FD4(W_, H_, A_)                \
  A_ = fdot2u((W_).x, (H_).x, A_);     \
  A_ = fdot2u((W_).y, (H_).y, A_);     \
  A_ = fdot2u((W_).z, (H_).z, A_);     \
  A_ = fdot2u((W_).w, (H_).w, A_);
// fused AGPR-read + dot block: non-volatile, temps die inside the block
#define AQ(r, k, A_)                                                      \
  asm("v_accvgpr_read_b32 %1, %5\n\t"                                     \
      "v_accvgpr_read_b32 %2, %6\n\t"                                     \
      "v_accvgpr_read_b32 %3, %7\n\t"                                     \
      "v_accvgpr_read_b32 %4, %8\n\t"                                     \
      "v_dot2_f32_f16 %0, %1, %9, %0\n\t"                                 \
      "v_dot2_f32_f16 %0, %2, %10, %0\n\t"                                \
      "v_dot2_f32_f16 %0, %3, %11, %0\n\t"                                \
      "v_dot2_f32_f16 %0, %4, %12, %0"                                    \
      : "+v"(A_), "=&v"(q0_), "=&v"(q1_), "=&v"(q2_), "=&v"(q3_)          \
      : "a"(ag##r##_##k##_0), "a"(ag##r##_##k##_1), "a"(ag##r##_##k##_2), \
        "a"(ag##r##_##k##_3), "v"(hq.x), "v"(hq.y), "v"(hq.z), "v"(hq.w))

      {  // k = 0 (VGPR)
        const uint4 hq = *(const uint4*)(hb + 0);
        FD4(w00, hq, a0) FD4(w10, hq, a1) FD4(w20, hq, a2) FD4(w30, hq, a3)
      }
      {  // k = 1 (VGPR)
        const uint4 hq = *(const uint4*)(hb + 16);
        FD4(w01, hq, a0) FD4(w11, hq, a1) FD4(w21, hq, a2) FD4(w31, hq, a3)
      }
      {  // k = 2 (AGPR)
        const uint4 hq = *(const uint4*)(hb + 32);
        uint32_t q0_, q1_, q2_, q3_;
        AQ(0, 2, a0); AQ(1, 2, a1); AQ(2, 2, a2); AQ(3, 2, a3);
      }
      {  // k = 3 (AGPR)
        const uint4 hq = *(const uint4*)(hb + 48);
        uint32_t q0_, q1_, q2_, q3_;
        AQ(0, 3, a0); AQ(1, 3, a1); AQ(2, 3, a2); AQ(3, 3, a3);
      }
      {  // k = 4 (AGPR)
        const uint4 hq = *(const uint4*)(hb + 64);
        uint32_t q0_, q1_, q2_, q3_;
        AQ(0, 4, a0); AQ(1, 4, a1); AQ(2, 4, a2); AQ(3, 4, a3);
      }
      {  // k = 5 (AGPR rows 0-2, LDS row 3)
        const uint4 hq = *(const uint4*)(hb + 80);
        uint32_t q0_, q1_, q2_, q3_;
        AQ(0, 5, a0); AQ(1, 5, a1); AQ(2, 5, a2);
        uint4 t = *(const uint4*)LWADDR(6);
        FD4(t, hq, a3)
      }
      {  // k = 6 (LDS)
        const uint4 hq = *(const uint4*)(hb + 96);
        uint4 t;
        t = *(const uint4*)LWADDR(0); FD4(t, hq, a0)
        t = *(const uint4*)LWADDR(2); FD4(t, hq, a1)
        t = *(const uint4*)LWADDR(4); FD4(t, hq, a2)
        t = *(const uint4*)LWADDR(7); FD4(t, hq, a3)
      }
      {  // k = 7 (LDS)
        const uint4 hq = *(const uint4*)(hb + 112);
        uint4 t;
        t = *(const uint4*)LWADDR(1); FD4(t, hq, a0)
        t = *(const uint4*)LWADDR(3); FD4(t, hq, a1)
        t = *(const uint4*)LWADDR(5); FD4(t, hq, a2)
        t = *(const uint4*)LWADDR(8); FD4(t, hq, a3)
      }

      // add xw into the gate row this lane owns, then butterfly over 4 lanes
      a0 += (sl == 0) ? xw : 0.f;
      a1 += (sl == 1) ? xw : 0.f;
      a2 += (sl == 2) ? xw : 0.f;
      a3 += (sl == 3) ? xw : 0.f;
      a0 += dppq<0xB1>(a0); a0 += dppq<0x4E>(a0);
      a1 += dppq<0xB1>(a1); a1 += dppq<0x4E>(a1);
      a2 += dppq<0xB1>(a2); a2 += dppq<0x4E>(a2);
      a3 += dppq<0xB1>(a3); a3 += dppq<0x4E>(a3);

      // update (all 4 lanes redundantly; consistent deterministic math)
      float ii = sigm(a0), ff = sigm(a1), tg = tanh_(a2), oo = sigm(a3);
      c_st = ff * c_st + ii * tg;
      float hn = oo * tanh_(c_st);
      h_last = hn;

      if (sl == 0 && uok) {
        // fp16 h into next-step buffer (segment u>>6, skewed)
        char* hw = smem + HB_BASE + ((tt + 1) & 1) * HBUF + (u >> 6) * HSEG +
                   (u & 63) * 2;
        *(_Float16*)hw = (_Float16)hn;
        if (L < 2)  // fp16 ring store (h is fp16-quantized on-path anyway)
          hBase[(size_t)(c & (HRING - 1)) * CH * HDIM + (size_t)tc * HDIM + u] =
              (_Float16)hn;
      }

      if (tc == CH - 1) {  // chunk end: full barrier then publish
        __syncthreads();
        if (tid == 0) {
          if (L < 2) arel(&F_HCNT(F, L), c + 1);
          if (L > 0) arel(&F_XWCON(F, L - 1), c + 1);
        }
      } else {
        step_barrier();  // h(next) writes visible; lgkm-only
      }
      xpc += RPAD;
    }

    if (L == 2) {  // final linear on h2[T-1]
      float* red = (float*)(smem + RED_BASE);
      if (sl == 0 && uok) red[u] = h_last;
      __syncthreads();
      if (tid == 0) {
        float s = bl[0];
        for (int j = 0; j < HDIM; ++j) s += red[j] * Wl[j];
        out[0] = s;
      }
    }
  } else {
    // ================= projection role (1024 threads, 16 waves) =================
    const int li = (bid - 3) / PP;
    const int p = (bid - 3) % PP;
    float* ldsH = (float*)smem;  // [64][257] f32
    const int lane = tid & 63, wid = tid >> 6;
    const float* WTl = WT + (size_t)li * HDIM * RPAD;
    const float* BVl = BV + (size_t)li * RPAD;

    for (int c = p; c < NC; c += PP) {
      if (tid == 0) {
        spin_ge(&F_HCNT(F, li), c + 1);
        if (c >= XRING) spin_ge(&F_XWCON(F, li), c - XRING + 1);
        acq_fence();
      }
      __syncthreads();
      const _Float16* hsrc = hRing + (size_t)li * HRING * CH * HDIM +
                             (size_t)(c & (HRING - 1)) * CH * HDIM;
      for (int t = wid; t < CH; t += 16)
        for (int j = lane; j < HDIM; j += 64)
          ldsH[t * 257 + j] = (float)hsrc[t * HDIM + j];
      __syncthreads();
      if (tid == 0) arel(&F_HDONE(F, li, p), c + 1);

      float* xdst = xwRing + (size_t)li * XRING * CH * RPAD +
                    (size_t)(c & (XRING - 1)) * CH * RPAD;
      const int rb0 = wid * 64;  // 16 waves x 64 rows = 1024 padded rows
      for (int grpq = 0; grpq < 8; ++grpq) {
        const int rb = rb0 + grpq * 8;
        float acc[8];
#pragma unroll
        for (int uq = 0; uq < 8; ++uq) acc[uq] = 0.f;
        const float* wp = WTl + rb;
        float4 wa4 = *(const float4*)(wp);
        float4 wb4 = *(const float4*)(wp + 4);
        for (int j = 0; j < HDIM; ++j) {
          int jn = (j + 1 < HDIM) ? j + 1 : HDIM - 1;
          float4 na = *(const float4*)(wp + (size_t)jn * RPAD);
          float4 nb = *(const float4*)(wp + (size_t)jn * RPAD + 4);
          float hj = ldsH[lane * 257 + j];
          acc[0] = fmaf(wa4.x, hj, acc[0]); acc[1] = fmaf(wa4.y, hj, acc[1]);
          acc[2] = fmaf(wa4.z, hj, acc[2]); acc[3] = fmaf(wa4.w, hj, acc[3]);
          acc[4] = fmaf(wb4.x, hj, acc[4]); acc[5] = fmaf(wb4.y, hj, acc[5]);
          acc[6] = fmaf(wb4.z, hj, acc[6]); acc[7] = fmaf(wb4.w, hj, acc[7]);
          wa4 = na; wb4 = nb;
        }
#pragma unroll
        for (int uq = 0; uq < 8; ++uq) {
          int r = rb + uq;
          if (r < GDIM) xdst[(size_t)lane * RPAD + r] = acc[uq] + BVl[r];
        }
      }
      __syncthreads();
      if (tid == 0) arel(&F_XWRDY(F, li, c), 1);
    }
  }
}

// ---------------- launch ----------------
extern "C" void kernel_launch(void* const* d_in, const int* in_sizes, int n_in,
                              void* d_out, int out_size, void* d_ws, size_t ws_size,
                              hipStream_t stream) {
  const float* x    = (const float*)d_in[0];
  const float* Wih0 = (const float*)d_in[1];
  const float* Whh0 = (const float*)d_in[2];
  const float* bih0 = (const float*)d_in[3];
  const float* bhh0 = (const float*)d_in[4];
  const float* Wih1 = (const float*)d_in[5];
  const float* Whh1 = (const float*)d_in[6];
  const float* bih1 = (const float*)d_in[7];
  const float* bhh1 = (const float*)d_in[8];
  const float* Wih2 = (const float*)d_in[9];
  const float* Whh2 = (const float*)d_in[10];
  const float* bih2 = (const float*)d_in[11];
  const float* bhh2 = (const float*)d_in[12];
  const float* Wl   = (const float*)d_in[13];
  const float* bl   = (const float*)d_in[14];
  const int T = in_sizes[0];

  char* ws = (char*)d_ws;
  int*      F   = (int*)ws;                                     // 4096 B flags
  float*    WT  = (float*)(ws + 4096);                          // 2,048,000 B
  float*    BV  = (float*)(ws + 4096 + 2048000);                // 8,192 B
  _Float16* hR  = (_Float16*)(ws + 4096 + 2048000 + 8192);      // 256,000 B fp16
  float*    xwR = (float*)(ws + 4096 + 2048000 + 8192 + 512000);  // 2,097,152 B

  hipMemsetAsync(F, 0, 4096, stream);  // reset protocol state every replay
  lstm_init<<<256, 256, 0, stream>>>(Wih1, bih1, bhh1, Wih2, bih2, bhh2, WT, BV);
  lstm_main<<<3 + 2 * PP, NTH, 0, stream>>>(
      x, Wih0, bih0, bhh0, Whh0, Whh1, Whh2, Wl, bl, F, WT, BV, hR, xwR,
      (float*)d_out, T);
}